// Round 8
// baseline (22739.207 us; speedup 1.0000x reference)
//
#include <hip/hip_runtime.h>
#include <hip/hip_cooperative_groups.h>
#include <stdint.h>

namespace cg = cooperative_groups;

// ---------------- threefry2x32 (exact JAX schedule) ----------------
__host__ __device__ inline void threefry2x32(uint32_t k0, uint32_t k1,
                                             uint32_t x0, uint32_t x1,
                                             uint32_t* o0, uint32_t* o1) {
  uint32_t ks2 = 0x1BD11BDAu ^ k0 ^ k1;
  x0 += k0; x1 += k1;
#define TF_R(x, r) (((x) << (r)) | ((x) >> (32 - (r))))
#define TF_ROUND(r) { x0 += x1; x1 = TF_R(x1, r); x1 ^= x0; }
  TF_ROUND(13) TF_ROUND(15) TF_ROUND(26) TF_ROUND(6)
  x0 += k1; x1 += ks2 + 1u;
  TF_ROUND(17) TF_ROUND(29) TF_ROUND(16) TF_ROUND(24)
  x0 += ks2; x1 += k0 + 2u;
  TF_ROUND(13) TF_ROUND(15) TF_ROUND(26) TF_ROUND(6)
  x0 += k0; x1 += k1 + 3u;
  TF_ROUND(17) TF_ROUND(29) TF_ROUND(16) TF_ROUND(24)
  x0 += k1; x1 += ks2 + 4u;
  TF_ROUND(13) TF_ROUND(15) TF_ROUND(26) TF_ROUND(6)
  x0 += ks2; x1 += k0 + 5u;
  *o0 = x0; *o1 = x1;
#undef TF_ROUND
#undef TF_R
}

__device__ __forceinline__ float wave_sum(float v) {
#pragma unroll
  for (int o = 32; o > 0; o >>= 1) v += __shfl_xor(v, o, 64);
  return v;
}
__device__ __forceinline__ float wave_max(float v) {
#pragma unroll
  for (int o = 32; o > 0; o >>= 1) v = fmaxf(v, __shfl_xor(v, o, 64));
  return v;
}

// ============================================================================
// ===========================  MEGAKERNEL PATH  ==============================
// ============================================================================

// ---- device GEMM phase: grid-strided 64x64 tiles, single-buffer LDS --------
// out = X @ W^T (+bias if !partial). X rows batch-mapped m -> (b=m/St, s=m%St).
// partial: raw partial to out[sp*M*ldo + m*ldo + n].
__device__ void dev_gemm(float* smem, const float* __restrict__ X,
                         long long xbs, int ldx, const float* __restrict__ W,
                         int ldw, const float* __restrict__ bias,
                         float* __restrict__ out, long long obs, int ldo,
                         int St, int M, int N, int K32, int splits, int relu,
                         int partial) {
  const int tid = threadIdx.x;
  const int mi = tid >> 4, ni = tid & 15, lr = tid >> 3, lc = (tid & 7) * 4;
  const int Mt = (M + 63) >> 6, Nt = N >> 6;
  const int njobs = Mt * Nt * splits;
  float (*Xl)[66] = (float (*)[66])smem;              // [32][66]
  float (*Wl)[66] = (float (*)[66])(smem + 32 * 66);  // [32][66]

  for (int job = blockIdx.x; job < njobs; job += gridDim.x) {
    const int mt = job % Mt;
    const int r2 = job / Mt;
    const int nt = r2 % Nt, sp = r2 / Nt;
    const int m0 = mt * 64, n0 = nt * 64;
    const long long kbase = (long long)sp * K32 * 32;

    const int mA = m0 + lr, mB = m0 + lr + 32;
    const float* xpA = nullptr;
    const float* xpB = nullptr;
    if (mA < M) {
      int b = mA / St, s = mA - b * St;
      xpA = X + (long long)b * xbs + (long long)s * ldx + kbase + lc;
    }
    if (mB < M) {
      int b = mB / St, s = mB - b * St;
      xpB = X + (long long)b * xbs + (long long)s * ldx + kbase + lc;
    }
    const float* wpA = W + (long long)(n0 + lr) * ldw + kbase + lc;
    const float* wpB = W + (long long)(n0 + lr + 32) * ldw + kbase + lc;

    // issue tile-0 loads BEFORE the barrier (latency hides under it)
    float4 xA = xpA ? *(const float4*)xpA : make_float4(0.f, 0.f, 0.f, 0.f);
    float4 xB = xpB ? *(const float4*)xpB : make_float4(0.f, 0.f, 0.f, 0.f);
    float4 wA = *(const float4*)wpA;
    float4 wB = *(const float4*)wpB;

    float acc[4][4];
#pragma unroll
    for (int i = 0; i < 4; ++i)
#pragma unroll
      for (int j = 0; j < 4; ++j) acc[i][j] = 0.f;

    __syncthreads();  // previous job's readers done with LDS
    Xl[lc + 0][lr] = xA.x; Xl[lc + 1][lr] = xA.y;
    Xl[lc + 2][lr] = xA.z; Xl[lc + 3][lr] = xA.w;
    Xl[lc + 0][lr + 32] = xB.x; Xl[lc + 1][lr + 32] = xB.y;
    Xl[lc + 2][lr + 32] = xB.z; Xl[lc + 3][lr + 32] = xB.w;
    Wl[lc + 0][lr] = wA.x; Wl[lc + 1][lr] = wA.y;
    Wl[lc + 2][lr] = wA.z; Wl[lc + 3][lr] = wA.w;
    Wl[lc + 0][lr + 32] = wB.x; Wl[lc + 1][lr + 32] = wB.y;
    Wl[lc + 2][lr + 32] = wB.z; Wl[lc + 3][lr + 32] = wB.w;
    __syncthreads();

    for (int i = 0; i < K32; ++i) {
      if (i + 1 < K32) {  // prefetch next tile into regs before compute
        int off = (i + 1) * 32;
        xA = xpA ? *(const float4*)(xpA + off) : make_float4(0.f, 0.f, 0.f, 0.f);
        xB = xpB ? *(const float4*)(xpB + off) : make_float4(0.f, 0.f, 0.f, 0.f);
        wA = *(const float4*)(wpA + off);
        wB = *(const float4*)(wpB + off);
      }
#pragma unroll
      for (int kk = 0; kk < 32; ++kk) {
        float4 xv = *(const float4*)&Xl[kk][mi * 4];
        float4 wv = *(const float4*)&Wl[kk][ni * 4];
        float xa[4] = {xv.x, xv.y, xv.z, xv.w};
        float wa[4] = {wv.x, wv.y, wv.z, wv.w};
#pragma unroll
        for (int a2 = 0; a2 < 4; ++a2)
#pragma unroll
          for (int c2 = 0; c2 < 4; ++c2)
            acc[a2][c2] = fmaf(xa[a2], wa[c2], acc[a2][c2]);
      }
      if (i + 1 < K32) {
        __syncthreads();
        Xl[lc + 0][lr] = xA.x; Xl[lc + 1][lr] = xA.y;
        Xl[lc + 2][lr] = xA.z; Xl[lc + 3][lr] = xA.w;
        Xl[lc + 0][lr + 32] = xB.x; Xl[lc + 1][lr + 32] = xB.y;
        Xl[lc + 2][lr + 32] = xB.z; Xl[lc + 3][lr + 32] = xB.w;
        Wl[lc + 0][lr] = wA.x; Wl[lc + 1][lr] = wA.y;
        Wl[lc + 2][lr] = wA.z; Wl[lc + 3][lr] = wA.w;
        Wl[lc + 0][lr + 32] = wB.x; Wl[lc + 1][lr + 32] = wB.y;
        Wl[lc + 2][lr + 32] = wB.z; Wl[lc + 3][lr + 32] = wB.w;
        __syncthreads();
      }
    }

    const int n = n0 + ni * 4;
    if (partial) {
      float* base = out + (long long)sp * M * ldo;
#pragma unroll
      for (int i = 0; i < 4; ++i) {
        int m = m0 + mi * 4 + i;
        if (m >= M) continue;
        *(float4*)(base + (long long)m * ldo + n) =
            make_float4(acc[i][0], acc[i][1], acc[i][2], acc[i][3]);
      }
    } else {
      float4 bv = *(const float4*)(bias + n);
#pragma unroll
      for (int i = 0; i < 4; ++i) {
        int m = m0 + mi * 4 + i;
        if (m >= M) continue;
        int b = m / St, s = m - b * St;
        float4 o;
        o.x = acc[i][0] + bv.x; o.y = acc[i][1] + bv.y;
        o.z = acc[i][2] + bv.z; o.w = acc[i][3] + bv.w;
        if (relu) {
          o.x = fmaxf(o.x, 0.f); o.y = fmaxf(o.y, 0.f);
          o.z = fmaxf(o.z, 0.f); o.w = fmaxf(o.w, 0.f);
        }
        *(float4*)(out + (long long)b * obs + (long long)s * ldo + n) = o;
      }
    }
  }
}

// ------- epilogue phase: sum split-K partials + bias (+res)(+relu)(+LN) -----
__device__ void dev_epi(float* smem, const float* __restrict__ P, int splits,
                        int M, int N, const float* __restrict__ bias,
                        const float* __restrict__ res, long long rbs, int ldr,
                        const float* __restrict__ lnw,
                        const float* __restrict__ lnb, float* __restrict__ out,
                        long long obs, int ldo, int St, int relu) {
  float* red = smem;
  const int tid = threadIdx.x;
  const int nch = N >> 10;
  const int njobs = M * nch;
  for (int job = blockIdx.x; job < njobs; job += gridDim.x) {
    __syncthreads();
    const int m = job / nch, ch = job - m * nch;
    const int b = m / St, s = m - b * St;
    const int n = ch * 1024 + tid * 4;
    const float* pr = P + (long long)m * N + n;
    float4 v = *(const float4*)pr;
    for (int sp = 1; sp < splits; ++sp) {
      float4 w2 = *(const float4*)(pr + (long long)sp * M * N);
      v.x += w2.x; v.y += w2.y; v.z += w2.z; v.w += w2.w;
    }
    float4 bv = *(const float4*)(bias + n);
    v.x += bv.x; v.y += bv.y; v.z += bv.z; v.w += bv.w;
    if (res) {
      float4 rv =
          *(const float4*)(res + (long long)b * rbs + (long long)s * ldr + n);
      v.x += rv.x; v.y += rv.y; v.z += rv.z; v.w += rv.w;
    }
    if (relu) {
      v.x = fmaxf(v.x, 0.f); v.y = fmaxf(v.y, 0.f);
      v.z = fmaxf(v.z, 0.f); v.w = fmaxf(v.w, 0.f);
    }
    if (lnw) {
      float sum = wave_sum(v.x + v.y + v.z + v.w);
      int wid = tid >> 6;
      if ((tid & 63) == 0) red[wid] = sum;
      __syncthreads();
      float mean = (red[0] + red[1] + red[2] + red[3]) * (1.f / 1024.f);
      float4 d;
      d.x = v.x - mean; d.y = v.y - mean; d.z = v.z - mean; d.w = v.w - mean;
      float s2 = wave_sum(d.x * d.x + d.y * d.y + d.z * d.z + d.w * d.w);
      __syncthreads();
      if ((tid & 63) == 0) red[wid] = s2;
      __syncthreads();
      float var = (red[0] + red[1] + red[2] + red[3]) * (1.f / 1024.f);
      float inv = rsqrtf(var + 1e-5f);
      float4 wv = *(const float4*)(lnw + tid * 4);
      float4 lb = *(const float4*)(lnb + tid * 4);
      v.x = d.x * inv * wv.x + lb.x;
      v.y = d.y * inv * wv.y + lb.y;
      v.z = d.z * inv * wv.z + lb.z;
      v.w = d.w * inv * wv.w + lb.w;
    }
    *(float4*)(out + (long long)b * obs + (long long)s * ldo + n) = v;
  }
}

// ------- attention phase: one wave per (b,h,sq), scores in registers --------
__device__ void dev_attn(const float* __restrict__ Qp, int q_rs, long long q_bs,
                         long long q_pstride, int q_nsplit,
                         const float* __restrict__ qbias,
                         const float* __restrict__ Kp, int k_rs, long long k_bs,
                         const float* __restrict__ Vp, int v_rs, long long v_bs,
                         float* __restrict__ Op, int o_rs, long long o_bs,
                         int Sq, int Skv) {
  const int lane = threadIdx.x & 63, wid = threadIdx.x >> 6;
  const int njobs = 2 * 8 * Sq;
  for (int job = blockIdx.x * 4 + wid; job < njobs; job += gridDim.x * 4) {
    int b = job / (8 * Sq);
    int rr = job - b * 8 * Sq;
    int h = rr / Sq;
    int sq = rr - h * Sq;
    const float* qrow =
        Qp + (long long)b * q_bs + (long long)sq * q_rs + h * 128;
    float q0 = qrow[lane], q1 = qrow[lane + 64];
    for (int sp = 1; sp < q_nsplit; ++sp) {
      const float* q2 = qrow + sp * q_pstride;
      q0 += q2[lane]; q1 += q2[lane + 64];
    }
    if (qbias) {
      q0 += qbias[h * 128 + lane];
      q1 += qbias[h * 128 + lane + 64];
    }
    // scores lane-distributed: lane k holds score k (and k+64)
    float s0v = -3.4e38f, s1v = -3.4e38f;
    const float* kb = Kp + (long long)b * k_bs + h * 128;
    for (int sk = 0; sk < Skv; ++sk) {
      const float* kr = kb + (long long)sk * k_rs;
      float p = fmaf(q0, kr[lane], q1 * kr[lane + 64]);
      p = wave_sum(p) * 0.08838834764831845f;  // 1/sqrt(128)
      if (sk < 64) {
        if (lane == sk) s0v = p;
      } else {
        if (lane == sk - 64) s1v = p;
      }
    }
    float m = wave_max(fmaxf(s0v, s1v));
    float e0 = expf(s0v - m);  // -inf -> 0
    float e1 = expf(s1v - m);
    float inv = 1.f / wave_sum(e0 + e1);
    float o0 = 0.f, o1 = 0.f;
    const float* vb = Vp + (long long)b * v_bs + h * 128;
    for (int sk = 0; sk < Skv; ++sk) {
      float w = (sk < 64) ? __shfl(e0, sk, 64) : __shfl(e1, sk - 64, 64);
      const float* vr = vb + (long long)sk * v_rs;
      o0 = fmaf(w, vr[lane], o0);
      o1 = fmaf(w, vr[lane + 64], o1);
    }
    float* orow = Op + (long long)b * o_bs + (long long)sq * o_rs + h * 128;
    orow[lane] = o0 * inv;
    orow[lane + 64] = o1 * inv;
  }
}

// ---------------- args ----------------
struct MArgs {
  const float *emb, *sa_in_w, *sa_in_b, *sa_out_w, *sa_out_b;
  const float *ca_in_w, *ca_in_b, *ca_out_w, *ca_out_b;
  const float *ff1_w, *ff1_b, *ff2_w, *ff2_b, *ln_w, *ln_b;
  const float *out_w, *out_b, *temp_w, *temp_b, *style_w, *style_b;
  float *ws, *out;
};

// ---------------- the megakernel ----------------
__global__ __launch_bounds__(256, 2) void mega_kernel(MArgs a) {
  cg::grid_group grid = cg::this_grid();
  __shared__ __align__(16) float smem[2 * 32 * 66];  // 16,896 B
  const int tid = threadIdx.x, bid = blockIdx.x, nb = gridDim.x;
  const int wid = tid >> 6, lane = tid & 63;

  float* cur = a.ws;                     // [2][72][1024]
  float* A = cur + 2 * 72 * 1024;        // [2][72][1024]
  float* Qb = A + 2 * 72 * 1024;         // [2][72][3072]
  float* Tb = Qb + 2 * 72 * 3072;        // [2][72][1024]
  float* Fb = Tb + 2 * 72 * 1024;        // [2][72][4096]
  float* cakv = Fb + 2 * 72 * 4096;      // [2][2][64][2048]
  float* Pp = cakv + 2 * 2 * 64 * 2048;  // split-K partials
  float* xmean = Pp + 2400000;
  float* stylev = xmean + 2048;
  float* tempv = stylev + 2048;
  float* toks_out = a.out;
  float* logits_out = toks_out + 16;

  // ---- P0: copy cur, xmean, temp, cross-attn K/V (independent) ----
  for (int idx = bid * 256 + tid; idx < 131072; idx += nb * 256) {
    int b = idx >> 16, r = idx & 65535;
    cur[(long long)b * 73728 + r] = a.emb[idx];
  }
  for (int idx = bid * 256 + tid; idx < 2048; idx += nb * 256) {
    int b = idx >> 10, d = idx & 1023;
    float s = 0.f;
    for (int ss = 0; ss < 64; ++ss) s += a.emb[b * 65536 + ss * 1024 + d];
    xmean[idx] = s * (1.f / 64.f);
  }
  if (bid < 2) {  // temperature
    int b = bid;
    float acc = 0.f;
    for (int s = wid; s < 64; s += 4) {
      const float* x = a.emb + b * 65536 + s * 1024;
      float p = 0.f;
#pragma unroll
      for (int it = 0; it < 4; ++it) {
        float4 xv = *(const float4*)(x + it * 256 + lane * 4);
        float4 wv = *(const float4*)(a.temp_w + it * 256 + lane * 4);
        p += xv.x * wv.x + xv.y * wv.y + xv.z * wv.z + xv.w * wv.w;
      }
      p = wave_sum(p);
      acc += 1.f / (1.f + expf(-(p + a.temp_b[0])));
    }
    if (lane == 0) smem[wid] = acc;
    __syncthreads();
    if (tid == 0)
      tempv[b] = (smem[0] + smem[1] + smem[2] + smem[3]) * (1.f / 64.f);
    __syncthreads();
  }
  for (int l = 0; l < 2; ++l)  // cross-attn K,V (constant memory input)
    dev_gemm(smem, a.emb, 64 * 1024, 1024,
             a.ca_in_w + (size_t)(l * 3072 + 1024) * 1024, 1024,
             a.ca_in_b + l * 3072 + 1024, cakv + (size_t)l * 2 * 64 * 2048,
             64 * 2048, 2048, 64, 128, 2048, 32, 1, 0, 0);
  grid.sync();

  // ---- style = xmean @ style_w^T + style_b (wave per row, 4 rows/block) ----
  for (int job = bid; job < 256; job += nb) {
    int d = job * 4 + wid;
    const float* wr = a.style_w + (long long)d * 1024;
    float a0 = 0.f, a1 = 0.f;
#pragma unroll
    for (int it = 0; it < 4; ++it) {
      float4 wv = *(const float4*)(wr + it * 256 + lane * 4);
      float4 x0 = *(const float4*)(xmean + it * 256 + lane * 4);
      float4 x1 = *(const float4*)(xmean + 1024 + it * 256 + lane * 4);
      a0 += wv.x * x0.x + wv.y * x0.y + wv.z * x0.z + wv.w * x0.w;
      a1 += wv.x * x1.x + wv.y * x1.y + wv.z * x1.z + wv.w * x1.w;
    }
    a0 = wave_sum(a0);
    a1 = wave_sum(a1);
    if (lane == 0) {
      stylev[d] = a0 + a.style_b[d];
      stylev[1024 + d] = a1 + a.style_b[d];
    }
  }
  grid.sync();

  // ---- decode loop ----
  for (int t = 0; t < 8; ++t) {
    const int St = 64 + t;
    const int M = 2 * St;
    for (int l = 0; l < 2; ++l) {
      const float* P0 = (l == 0) ? cur : A;
      // self-attn QKV: split-K x4 -> epi bias -> Qb
      dev_gemm(smem, P0, 72 * 1024, 1024,
               a.sa_in_w + (size_t)l * 3072 * 1024, 1024, nullptr, Pp, 0, 3072,
               St, M, 3072, 8, 4, 0, 1);
      grid.sync();
      dev_epi(smem, Pp, 4, M, 3072, a.sa_in_b + l * 3072, nullptr, 0, 0,
              nullptr, nullptr, Qb, 72 * 3072, 3072, St, 0);
      grid.sync();
      dev_attn(Qb, 3072, 72 * 3072, 0, 1, nullptr, Qb + 1024, 3072, 72 * 3072,
               Qb + 2048, 3072, 72 * 3072, Tb, 1024, 72 * 1024, St, St);
      grid.sync();
      // out-proj: split-K x8 -> epi bias+res+LN0 -> A
      dev_gemm(smem, Tb, 72 * 1024, 1024,
               a.sa_out_w + (size_t)l * 1024 * 1024, 1024, nullptr, Pp, 0,
               1024, St, M, 1024, 4, 8, 0, 1);
      grid.sync();
      dev_epi(smem, Pp, 8, M, 1024, a.sa_out_b + l * 1024, P0, 72 * 1024,
              1024, a.ln_w + (l * 3 + 0) * 1024, a.ln_b + (l * 3 + 0) * 1024,
              A, 72 * 1024, 1024, St, 0);
      grid.sync();
      // cross-attn Q: split-K x4, partials+bias summed inside attn
      dev_gemm(smem, A, 72 * 1024, 1024, a.ca_in_w + (size_t)l * 3072 * 1024,
               1024, nullptr, Pp, 0, 1024, St, M, 1024, 8, 4, 0, 1);
      grid.sync();
      dev_attn(Pp, 1024, (long long)St * 1024, (long long)M * 1024, 4,
               a.ca_in_b + l * 3072, cakv + (size_t)l * 2 * 64 * 2048, 2048,
               64 * 2048, cakv + (size_t)l * 2 * 64 * 2048 + 1024, 2048,
               64 * 2048, Tb, 1024, 72 * 1024, St, 64);
      grid.sync();
      // ca out-proj: split-K x8 -> epi bias+res+LN1 -> A
      dev_gemm(smem, Tb, 72 * 1024, 1024,
               a.ca_out_w + (size_t)l * 1024 * 1024, 1024, nullptr, Pp, 0,
               1024, St, M, 1024, 4, 8, 0, 1);
      grid.sync();
      dev_epi(smem, Pp, 8, M, 1024, a.ca_out_b + l * 1024, A, 72 * 1024, 1024,
              a.ln_w + (l * 3 + 1) * 1024, a.ln_b + (l * 3 + 1) * 1024, A,
              72 * 1024, 1024, St, 0);
      grid.sync();
      // FFN1: split-K x2 -> epi bias+relu -> Fb
      dev_gemm(smem, A, 72 * 1024, 1024, a.ff1_w + (size_t)l * 4096 * 1024,
               1024, nullptr, Pp, 0, 4096, St, M, 4096, 16, 2, 0, 1);
      grid.sync();
      dev_epi(smem, Pp, 2, M, 4096, a.ff1_b + l * 4096, nullptr, 0, 0,
              nullptr, nullptr, Fb, 72 * 4096, 4096, St, 1);
      grid.sync();
      // FFN2: split-K x8 -> epi bias+res+LN2 -> A
      dev_gemm(smem, Fb, 72 * 4096, 4096, a.ff2_w + (size_t)l * 1024 * 4096,
               4096, nullptr, Pp, 0, 1024, St, M, 1024, 16, 8, 0, 1);
      grid.sync();
      dev_epi(smem, Pp, 8, M, 1024, a.ff2_b + l * 1024, A, 72 * 1024, 1024,
              a.ln_w + (l * 3 + 2) * 1024, a.ln_b + (l * 3 + 2) * 1024, A,
              72 * 1024, 1024, St, 0);
      grid.sync();
    }

    // ---- logits: z = A[:, St-1] + style, one wave per vocab row ----
    {
      const float* a0p = A + (long long)(St - 1) * 1024;
      const float* a1p = A + 73728 + (long long)(St - 1) * 1024;
      for (int job = bid; job < 8000; job += nb) {
        int n = job * 4 + wid;
        const float* wr = a.out_w + (long long)n * 1024;
        float acc0 = 0.f, acc1 = 0.f;
#pragma unroll
        for (int it = 0; it < 4; ++it) {
          int off = it * 256 + lane * 4;
          float4 wv = *(const float4*)(wr + off);
          float4 x0 = *(const float4*)(a0p + off);
          float4 s0 = *(const float4*)(stylev + off);
          float4 x1 = *(const float4*)(a1p + off);
          float4 s1 = *(const float4*)(stylev + 1024 + off);
          acc0 += wv.x * (x0.x + s0.x) + wv.y * (x0.y + s0.y) +
                  wv.z * (x0.z + s0.z) + wv.w * (x0.w + s0.w);
          acc1 += wv.x * (x1.x + s1.x) + wv.y * (x1.y + s1.y) +
                  wv.z * (x1.z + s1.z) + wv.w * (x1.w + s1.w);
        }
        acc0 = wave_sum(acc0);
        acc1 = wave_sum(acc1);
        if (lane == 0) {
          float bb = a.out_b[n];
          logits_out[(long long)(0 * 8 + t) * 32000 + n] = (acc0 + bb) / tempv[0];
          logits_out[(long long)(1 * 8 + t) * 32000 + n] = (acc1 + bb) / tempv[1];
        }
      }
    }
    grid.sync();

    // ---- Gumbel argmax sample (exact partitionable threefry) + append ----
    if (bid < 2) {
      int b = bid;
      uint32_t fk0, fk1;
      threefry2x32(0u, 42u, 0u, (uint32_t)t, &fk0, &fk1);
      const float* lg = logits_out + (long long)(b * 8 + t) * 32000;
      float best = -3.4e38f;
      int bi2 = 0x7fffffff;
      for (int n = tid; n < 32000; n += 256) {
        uint32_t r0, r1;
        threefry2x32(fk0, fk1, 0u, (uint32_t)(b * 32000 + n), &r0, &r1);
        uint32_t bits = (r0 ^ r1) >> 9;
        float u = __uint_as_float(0x3f800000u | bits) - 1.0f;
        if (u < 1.1754944e-38f) u = 1.1754944e-38f;
        float g = -logf(-logf(u));
        float val = lg[n] + g;
        if (val > best) { best = val; bi2 = n; }
      }
      float* bv = smem;
      int* bix = (int*)(smem + 256);
      __syncthreads();
      bv[tid] = best;
      bix[tid] = bi2;
      __syncthreads();
      for (int s = 128; s > 0; s >>= 1) {
        if (tid < s) {
          float ov = bv[tid + s];
          int oi = bix[tid + s];
          if (ov > bv[tid] || (ov == bv[tid] && oi < bix[tid])) {
            bv[tid] = ov;
            bix[tid] = oi;
          }
        }
        __syncthreads();
      }
      int tok = bix[0];
      if (tid == 0) toks_out[b * 8 + t] = (float)tok;
      for (int d = tid; d < 1024; d += 256)
        cur[(long long)b * 73728 + (long long)St * 1024 + d] =
            a.out_w[(long long)tok * 1024 + d];
    }
    grid.sync();
  }
}

// ============================================================================
// =====================  FALLBACK MULTI-KERNEL PATH  =========================
// ============================================================================

__global__ __launch_bounds__(256) void gemm2_kernel(
    const float* __restrict__ X, long long xbs, int ldx,
    const float* __restrict__ W, int ldw,
    const float* __restrict__ bias,
    float* __restrict__ out, long long obs, int ldo,
    int St, int M, int N, int K32, int relu, int partial) {
  __shared__ __align__(16) float Xl[2][32][68];
  __shared__ __align__(16) float Wl[2][32][68];
  const int tid = threadIdx.x;
  const int m0 = blockIdx.x * 64;
  const int n0 = blockIdx.y * 64;
  const long long kbase = (long long)blockIdx.z * K32 * 32;
  const int mi = tid >> 4, ni = tid & 15, lr = tid >> 3, lc = (tid & 7) * 4;

  const int mA = m0 + lr, mB = m0 + lr + 32;
  const float* xpA = nullptr;
  const float* xpB = nullptr;
  if (mA < M) {
    int b = mA / St, s = mA - b * St;
    xpA = X + (long long)b * xbs + (long long)s * ldx + kbase + lc;
  }
  if (mB < M) {
    int b = mB / St, s = mB - b * St;
    xpB = X + (long long)b * xbs + (long long)s * ldx + kbase + lc;
  }
  const float* wpA = W + (long long)(n0 + lr) * ldw + kbase + lc;
  const float* wpB = W + (long long)(n0 + lr + 32) * ldw + kbase + lc;

  float4 xA = xpA ? *(const float4*)xpA : make_float4(0.f, 0.f, 0.f, 0.f);
  float4 xB = xpB ? *(const float4*)xpB : make_float4(0.f, 0.f, 0.f, 0.f);
  float4 wA = *(const float4*)wpA;
  float4 wB = *(const float4*)wpB;

  float acc[4][4];
#pragma unroll
  for (int i = 0; i < 4; ++i)
#pragma unroll
    for (int j = 0; j < 4; ++j) acc[i][j] = 0.f;

  Xl[0][lc + 0][lr] = xA.x; Xl[0][lc + 1][lr] = xA.y;
  Xl[0][lc + 2][lr] = xA.z; Xl[0][lc + 3][lr] = xA.w;
  Xl[0][lc + 0][lr + 32] = xB.x; Xl[0][lc + 1][lr + 32] = xB.y;
  Xl[0][lc + 2][lr + 32] = xB.z; Xl[0][lc + 3][lr + 32] = xB.w;
  Wl[0][lc + 0][lr] = wA.x; Wl[0][lc + 1][lr] = wA.y;
  Wl[0][lc + 2][lr] = wA.z; Wl[0][lc + 3][lr] = wA.w;
  Wl[0][lc + 0][lr + 32] = wB.x; Wl[0][lc + 1][lr + 32] = wB.y;
  Wl[0][lc + 2][lr + 32] = wB.z; Wl[0][lc + 3][lr + 32] = wB.w;
  __syncthreads();

  for (int i = 0; i < K32; ++i) {
    if (i + 1 < K32) {
      int off = (i + 1) * 32;
      xA = xpA ? *(const float4*)(xpA + off) : make_float4(0.f, 0.f, 0.f, 0.f);
      xB = xpB ? *(const float4*)(xpB + off) : make_float4(0.f, 0.f, 0.f, 0.f);
      wA = *(const float4*)(wpA + off);
      wB = *(const float4*)(wpB + off);
    }
    const int cur = i & 1;
#pragma unroll
    for (int kk = 0; kk < 32; ++kk) {
      float4 xv = *(const float4*)&Xl[cur][kk][mi * 4];
      float4 wv = *(const float4*)&Wl[cur][kk][ni * 4];
      float xa[4] = {xv.x, xv.y, xv.z, xv.w};
      float wa[4] = {wv.x, wv.y, wv.z, wv.w};
#pragma unroll
      for (int a = 0; a < 4; ++a)
#pragma unroll
        for (int c = 0; c < 4; ++c) acc[a][c] = fmaf(xa[a], wa[c], acc[a][c]);
    }
    if (i + 1 < K32) {
      __syncthreads();
      const int nxt = cur ^ 1;
      Xl[nxt][lc + 0][lr] = xA.x; Xl[nxt][lc + 1][lr] = xA.y;
      Xl[nxt][lc + 2][lr] = xA.z; Xl[nxt][lc + 3][lr] = xA.w;
      Xl[nxt][lc + 0][lr + 32] = xB.x; Xl[nxt][lc + 1][lr + 32] = xB.y;
      Xl[nxt][lc + 2][lr + 32] = xB.z; Xl[nxt][lc + 3][lr + 32] = xB.w;
      Wl[nxt][lc + 0][lr] = wA.x; Wl[nxt][lc + 1][lr] = wA.y;
      Wl[nxt][lc + 2][lr] = wA.z; Wl[nxt][lc + 3][lr] = wA.w;
      Wl[nxt][lc + 0][lr + 32] = wB.x; Wl[nxt][lc + 1][lr + 32] = wB.y;
      Wl[nxt][lc + 2][lr + 32] = wB.z; Wl[nxt][lc + 3][lr + 32] = wB.w;
      __syncthreads();
    }
  }

  const int n = n0 + ni * 4;
  if (partial) {
    float* base = out + (long long)blockIdx.z * M * ldo;
#pragma unroll
    for (int i = 0; i < 4; ++i) {
      int m = m0 + mi * 4 + i;
      if (m >= M) continue;
      *(float4*)(base + (long long)m * ldo + n) =
          make_float4(acc[i][0], acc[i][1], acc[i][2], acc[i][3]);
    }
  } else {
    float4 bv = *(const float4*)(bias + n);
#pragma unroll
    for (int i = 0; i < 4; ++i) {
      int m = m0 + mi * 4 + i;
      if (m >= M) continue;
      int b = m / St, s = m - b * St;
      float4 o;
      o.x = acc[i][0] + bv.x; o.y = acc[i][1] + bv.y;
      o.z = acc[i][2] + bv.z; o.w = acc[i][3] + bv.w;
      if (relu) {
        o.x = fmaxf(o.x, 0.f); o.y = fmaxf(o.y, 0.f);
        o.z = fmaxf(o.z, 0.f); o.w = fmaxf(o.w, 0.f);
      }
      *(float4*)(out + (long long)b * obs + (long long)s * ldo + n) = o;
    }
  }
}

__global__ __launch_bounds__(256) void epi_kernel(
    const float* __restrict__ P, int splits, int M, int N,
    const float* __restrict__ bias,
    const float* __restrict__ res, long long rbs, int ldr,
    const float* __restrict__ lnw, const float* __restrict__ lnb,
    float* __restrict__ out, long long obs, int ldo, int St, int relu) {
  __shared__ float red[4];
  const int m = blockIdx.x;
  const int b = m / St, s = m - b * St;
  const int n = blockIdx.y * 1024 + threadIdx.x * 4;
  const float* pr = P + (long long)m * N + n;
  float4 v = *(const float4*)pr;
  for (int sp = 1; sp < splits; ++sp) {
    float4 w2 = *(const float4*)(pr + (long long)sp * M * N);
    v.x += w2.x; v.y += w2.y; v.z += w2.z; v.w += w2.w;
  }
  float4 bv = *(const float4*)(bias + n);
  v.x += bv.x; v.y += bv.y; v.z += bv.z; v.w += bv.w;
  if (res) {
    float4 rv = *(const float4*)(res + (long long)b * rbs + (long long)s * ldr + n);
    v.x += rv.x; v.y += rv.y; v.z += rv.z; v.w += rv.w;
  }
  if (relu) {
    v.x = fmaxf(v.x, 0.f); v.y = fmaxf(v.y, 0.f);
    v.z = fmaxf(v.z, 0.f); v.w = fmaxf(v.w, 0.f);
  }
  if (lnw) {
    const int tid = threadIdx.x;
    float sum = wave_sum(v.x + v.y + v.z + v.w);
    int wid = tid >> 6;
    if ((tid & 63) == 0) red[wid] = sum;
    __syncthreads();
    float mean = (red[0] + red[1] + red[2] + red[3]) * (1.f / 1024.f);
    float4 d;
    d.x = v.x - mean; d.y = v.y - mean; d.z = v.z - mean; d.w = v.w - mean;
    float s2 = wave_sum(d.x * d.x + d.y * d.y + d.z * d.z + d.w * d.w);
    __syncthreads();
    if ((tid & 63) == 0) red[wid] = s2;
    __syncthreads();
    float var = (red[0] + red[1] + red[2] + red[3]) * (1.f / 1024.f);
    float inv = rsqrtf(var + 1e-5f);
    float4 wv = *(const float4*)(lnw + tid * 4);
    float4 lb = *(const float4*)(lnb + tid * 4);
    v.x = d.x * inv * wv.x + lb.x;
    v.y = d.y * inv * wv.y + lb.y;
    v.z = d.z * inv * wv.z + lb.z;
    v.w = d.w * inv * wv.w + lb.w;
  }
  *(float4*)(out + (long long)b * obs + (long long)s * ldo + n) = v;
}

__global__ __launch_bounds__(64) void attn_kernel(
    const float* __restrict__ Qp, int q_rs, long long q_bs,
    long long q_pstride, int q_nsplit,
    const float* __restrict__ qbias,
    const float* __restrict__ Kp, int k_rs, long long k_bs,
    const float* __restrict__ Vp, int v_rs, long long v_bs,
    float* __restrict__ Op, int o_rs, long long o_bs,
    int Sq, int Skv) {
  const int lane = threadIdx.x;
  int bid = blockIdx.x;
  int b = bid / (8 * Sq);
  int rr = bid - b * 8 * Sq;
  int h = rr / Sq;
  int sq = rr - h * Sq;
  const float* qrow = Qp + (long long)b * q_bs + (long long)sq * q_rs + h * 128;
  float q0 = qrow[lane], q1 = qrow[lane + 64];
  for (int sp = 1; sp < q_nsplit; ++sp) {
    const float* q2 = qrow + sp * q_pstride;
    q0 += q2[lane]; q1 += q2[lane + 64];
  }
  if (qbias) {
    q0 += qbias[h * 128 + lane]; q1 += qbias[h * 128 + lane + 64];
  }
  __shared__ float sc[72];
  const float* kb = Kp + (long long)b * k_bs + h * 128;
  for (int sk = 0; sk < Skv; ++sk) {
    const float* kr = kb + (long long)sk * k_rs;
    float p = fmaf(q0, kr[lane], q1 * kr[lane + 64]);
    p = wave_sum(p);
    if (lane == 0) sc[sk] = p * 0.08838834764831845f;
  }
  __syncthreads();
  float m = -3.4e38f;
  for (int i = lane; i < Skv; i += 64) m = fmaxf(m, sc[i]);
  m = wave_max(m);
  float ssum = 0.f;
  for (int i = lane; i < Skv; i += 64) {
    float e = expf(sc[i] - m);
    sc[i] = e;
    ssum += e;
  }
  ssum = wave_sum(ssum);
  __syncthreads();
  float o0 = 0.f, o1 = 0.f;
  const float* vb = Vp + (long long)b * v_bs + h * 128;
  for (int sk = 0; sk < Skv; ++sk) {
    float w = sc[sk];
    const float* vr = vb + (long long)sk * v_rs;
    o0 = fmaf(w, vr[lane], o0);
    o1 = fmaf(w, vr[lane + 64], o1);
  }
  float inv = 1.f / ssum;
  float* orow = Op + (long long)b * o_bs + (long long)sq * o_rs + h * 128;
  orow[lane] = o0 * inv;
  orow[lane + 64] = o1 * inv;
}

__global__ __launch_bounds__(256) void copy_cur_kernel(
    const float* __restrict__ emb, float* __restrict__ cur) {
  int idx = blockIdx.x * 256 + threadIdx.x;
  int b = idx >> 16;
  int r = idx & 65535;
  cur[(long long)b * 73728 + r] = emb[idx];
}

__global__ __launch_bounds__(256) void xmean_kernel(
    const float* __restrict__ emb, float* __restrict__ xmean) {
  int idx = blockIdx.x * 256 + threadIdx.x;
  int b = idx >> 10, d = idx & 1023;
  float s = 0.f;
  for (int ss = 0; ss < 64; ++ss) s += emb[b * 65536 + ss * 1024 + d];
  xmean[idx] = s * (1.f / 64.f);
}

__global__ __launch_bounds__(256) void temp_kernel(
    const float* __restrict__ emb, const float* __restrict__ tw,
    const float* __restrict__ tb, float* __restrict__ tempv) {
  __shared__ float red[4];
  int b = blockIdx.x;
  int wid = threadIdx.x >> 6, lane = threadIdx.x & 63;
  float acc = 0.f;
  for (int s = wid; s < 64; s += 4) {
    const float* x = emb + b * 65536 + s * 1024;
    float p = 0.f;
#pragma unroll
    for (int it = 0; it < 4; ++it) {
      float4 xv = *(const float4*)(x + it * 256 + lane * 4);
      float4 wv = *(const float4*)(tw + it * 256 + lane * 4);
      p += xv.x * wv.x + xv.y * wv.y + xv.z * wv.z + xv.w * wv.w;
    }
    p = wave_sum(p);
    acc += 1.f / (1.f + expf(-(p + tb[0])));
  }
  if (lane == 0) red[wid] = acc;
  __syncthreads();
  if (threadIdx.x == 0)
    tempv[b] = (red[0] + red[1] + red[2] + red[3]) * (1.f / 64.f);
}

__global__ __launch_bounds__(256) void style_kernel(
    const float* __restrict__ xmean, const float* __restrict__ sw,
    const float* __restrict__ sb, float* __restrict__ stylev) {
  int wid = threadIdx.x >> 6, lane = threadIdx.x & 63;
  int d = blockIdx.x * 4 + wid;
  const float* wr = sw + (long long)d * 1024;
  float a0 = 0.f, a1 = 0.f;
#pragma unroll
  for (int it = 0; it < 4; ++it) {
    float4 wv = *(const float4*)(wr + it * 256 + lane * 4);
    float4 x0 = *(const float4*)(xmean + it * 256 + lane * 4);
    float4 x1 = *(const float4*)(xmean + 1024 + it * 256 + lane * 4);
    a0 += wv.x * x0.x + wv.y * x0.y + wv.z * x0.z + wv.w * x0.w;
    a1 += wv.x * x1.x + wv.y * x1.y + wv.z * x1.z + wv.w * x1.w;
  }
  a0 = wave_sum(a0);
  a1 = wave_sum(a1);
  if (lane == 0) {
    stylev[d] = a0 + sb[d];
    stylev[1024 + d] = a1 + sb[d];
  }
}

__global__ __launch_bounds__(256) void logits_kernel(
    const float* __restrict__ A, const float* __restrict__ stylev, int St,
    const float* __restrict__ Wo, const float* __restrict__ bo,
    const float* __restrict__ tempv, float* __restrict__ outl, int t) {
  int wid = threadIdx.x >> 6, lane = threadIdx.x & 63;
  int n = blockIdx.x * 4 + wid;
  const float* wr = Wo + (long long)n * 1024;
  const float* a0p = A + (long long)(St - 1) * 1024;
  const float* a1p = A + 73728 + (long long)(St - 1) * 1024;
  float a0 = 0.f, a1 = 0.f;
#pragma unroll
  for (int it = 0; it < 4; ++it) {
    int off = it * 256 + lane * 4;
    float4 wv = *(const float4*)(wr + off);
    float4 x0 = *(const float4*)(a0p + off);
    float4 s0 = *(const float4*)(stylev + off);
    float4 x1 = *(const float4*)(a1p + off);
    float4 s1 = *(const float4*)(stylev + 1024 + off);
    a0 += wv.x * (x0.x + s0.x) + wv.y * (x0.y + s0.y) + wv.z * (x0.z + s0.z) +
          wv.w * (x0.w + s0.w);
    a1 += wv.x * (x1.x + s1.x) + wv.y * (x1.y + s1.y) + wv.z * (x1.z + s1.z) +
          wv.w * (x1.w + s1.w);
  }
  a0 = wave_sum(a0);
  a1 = wave_sum(a1);
  if (lane == 0) {
    float bb = bo[n];
    outl[(long long)(0 * 8 + t) * 32000 + n] = (a0 + bb) / tempv[0];
    outl[(long long)(1 * 8 + t) * 32000 + n] = (a1 + bb) / tempv[1];
  }
}

__global__ __launch_bounds__(1024) void sample_kernel(
    const float* __restrict__ logits, const float* __restrict__ Wo,
    float* __restrict__ tok_f, float* __restrict__ cur, int St,
    uint32_t fk0, uint32_t fk1, int t) {
  int b = blockIdx.x;
  const float* lg = logits + (long long)(b * 8 + t) * 32000;
  float best = -3.4e38f;
  int bi = 0x7fffffff;
  for (int n = threadIdx.x; n < 32000; n += 1024) {
    uint32_t r0, r1;
    threefry2x32(fk0, fk1, 0u, (uint32_t)(b * 32000 + n), &r0, &r1);
    uint32_t bits = (r0 ^ r1) >> 9;
    float u = __uint_as_float(0x3f800000u | bits) - 1.0f;
    if (u < 1.1754944e-38f) u = 1.1754944e-38f;
    float g = -logf(-logf(u));
    float val = lg[n] + g;
    if (val > best) { best = val; bi = n; }
  }
  __shared__ float bv[1024];
  __shared__ int bix[1024];
  bv[threadIdx.x] = best;
  bix[threadIdx.x] = bi;
  __syncthreads();
  for (int s = 512; s > 0; s >>= 1) {
    if (threadIdx.x < s) {
      float ov = bv[threadIdx.x + s];
      int oi = bix[threadIdx.x + s];
      if (ov > bv[threadIdx.x] ||
          (ov == bv[threadIdx.x] && oi < bix[threadIdx.x])) {
        bv[threadIdx.x] = ov;
        bix[threadIdx.x] = oi;
      }
    }
    __syncthreads();
  }
  int tok = bix[0];
  if (threadIdx.x == 0) tok_f[b * 8 + t] = (float)tok;
  cur[(long long)b * 73728 + (long long)St * 1024 + threadIdx.x] =
      Wo[(long long)tok * 1024 + threadIdx.x];
}

static inline void g2(hipStream_t st, const float* X, long long xbs, int ldx,
                      const float* W, int ldw, const float* bias, float* out,
                      long long obs, int ldo, int St, int M, int N, int K,
                      int splits, int relu, int partial) {
  dim3 grid((unsigned)((M + 63) / 64), (unsigned)(N / 64), (unsigned)splits);
  gemm2_kernel<<<grid, 256, 0, st>>>(X, xbs, ldx, W, ldw, bias, out, obs, ldo,
                                     St, M, N, K / (32 * splits), relu,
                                     partial);
}

static inline void epi(hipStream_t st, const float* P, int splits, int M,
                       int N, const float* bias, const float* res,
                       long long rbs, int ldr, const float* lnw,
                       const float* lnb, float* out, long long obs, int ldo,
                       int St, int relu) {
  dim3 grid((unsigned)M, (unsigned)(N / 1024));
  epi_kernel<<<grid, 256, 0, st>>>(P, splits, M, N, bias, res, rbs, ldr, lnw,
                                   lnb, out, obs, ldo, St, relu);
}

static void run_fallback(const MArgs& a, hipStream_t stream) {
  float* cur = a.ws;
  float* A = cur + 2 * 72 * 1024;
  float* Qb = A + 2 * 72 * 1024;
  float* Tb = Qb + 2 * 72 * 3072;
  float* Fb = Tb + 2 * 72 * 1024;
  float* cakv = Fb + 2 * 72 * 4096;
  float* Pp = cakv + 2 * 2 * 64 * 2048;
  float* xmean = Pp + 2400000;
  float* stylev = xmean + 2048;
  float* tempv = stylev + 2048;
  float* toks_out = a.out;
  float* logits_out = toks_out + 16;

  copy_cur_kernel<<<512, 256, 0, stream>>>(a.emb, cur);
  xmean_kernel<<<8, 256, 0, stream>>>(a.emb, xmean);
  temp_kernel<<<2, 256, 0, stream>>>(a.emb, a.temp_w, a.temp_b, tempv);
  style_kernel<<<256, 256, 0, stream>>>(xmean, a.style_w, a.style_b, stylev);
  for (int l = 0; l < 2; ++l)
    g2(stream, a.emb, 64 * 1024, 1024,
       a.ca_in_w + (size_t)(l * 3072 + 1024) * 1024, 1024,
       a.ca_in_b + l * 3072 + 1024, cakv + (size_t)l * 2 * 64 * 2048,
       64 * 2048, 2048, 64, 128, 2048, 1024, 1, 0, 0);

  for (int t = 0; t < 8; ++t) {
    int St = 64 + t;
    int M = 2 * St;
    for (int l = 0; l < 2; ++l) {
      const float* P0 = (l == 0) ? cur : A;
      g2(stream, P0, 72 * 1024, 1024, a.sa_in_w + (size_t)l * 3072 * 1024,
         1024, nullptr, Pp, 0, 3072, St, M, 3072, 1024, 4, 0, 1);
      epi(stream, Pp, 4, M, 3072, a.sa_in_b + l * 3072, nullptr, 0, 0,
          nullptr, nullptr, Qb, 72 * 3072, 3072, St, 0);
      attn_kernel<<<2 * 8 * St, 64, 0, stream>>>(
          Qb, 3072, 72 * 3072, 0, 1, nullptr, Qb + 1024, 3072, 72 * 3072,
          Qb + 2048, 3072, 72 * 3072, Tb, 1024, 72 * 1024, St, St);
      g2(stream, Tb, 72 * 1024, 1024, a.sa_out_w + (size_t)l * 1024 * 1024,
         1024, nullptr, Pp, 0, 1024, St, M, 1024, 1024, 8, 0, 1);
      epi(stream, Pp, 8, M, 1024, a.sa_out_b + l * 1024, P0, 72 * 1024, 1024,
          a.ln_w + (l * 3 + 0) * 1024, a.ln_b + (l * 3 + 0) * 1024, A,
          72 * 1024, 1024, St, 0);
      g2(stream, A, 72 * 1024, 1024, a.ca_in_w + (size_t)l * 3072 * 1024,
         1024, nullptr, Pp, 0, 1024, St, M, 1024, 1024, 4, 0, 1);
      attn_kernel<<<2 * 8 * St, 64, 0, stream>>>(
          Pp, 1024, (long long)St * 1024, (long long)M * 1024, 4,
          a.ca_in_b + l * 3072, cakv + (size_t)l * 2 * 64 * 2048, 2048,
          64 * 2048, cakv + (size_t)l * 2 * 64 * 2048 + 1024, 2048, 64 * 2048,
          Tb, 1024, 72 * 1024, St, 64);
      g2(stream, Tb, 72 * 1024, 1024, a.ca_out_w + (size_t)l * 1024 * 1024,
         1024, nullptr, Pp, 0, 1024, St, M, 1024, 1024, 8, 0, 1);
      epi(stream, Pp, 8, M, 1024, a.ca_out_b + l * 1024, A, 72 * 1024, 1024,
          a.ln_w + (l * 3 + 1) * 1024, a.ln_b + (l * 3 + 1) * 1024, A,
          72 * 1024, 1024, St, 0);
      g2(stream, A, 72 * 1024, 1024, a.ff1_w + (size_t)l * 4096 * 1024, 1024,
         nullptr, Pp, 0, 4096, St, M, 4096, 1024, 4, 0, 1);
      epi(stream, Pp, 4, M, 4096, a.ff1_b + l * 4096, nullptr, 0, 0, nullptr,
          nullptr, Fb, 72 * 4096, 4096, St, 1);
      g2(stream, Fb, 72 * 4096, 4096, a.ff2_w + (size_t)l * 1024 * 4096, 4096,
         nullptr, Pp, 0, 1024, St, M, 1024, 4096, 16, 0, 1);
      epi(stream, Pp, 16, M, 1024, a.ff2_b + l * 1024, A, 72 * 1024, 1024,
          a.ln_w + (l * 3 + 2) * 1024, a.ln_b + (l * 3 + 2) * 1024, A,
          72 * 1024, 1024, St, 0);
    }
    logits_kernel<<<8000, 256, 0, stream>>>(A, stylev, St, a.out_w, a.out_b,
                                            tempv, logits_out, t);
    uint32_t fk0, fk1;
    threefry2x32(0u, 42u, 0u, (uint32_t)t, &fk0, &fk1);
    sample_kernel<<<2, 1024, 0, stream>>>(logits_out, a.out_w, toks_out, cur,
                                          St, fk0, fk1, t);
  }
}

// ============================================================================
extern "C" void kernel_launch(void* const* d_in, const int* in_sizes, int n_in,
                              void* d_out, int out_size, void* d_ws,
                              size_t ws_size, hipStream_t stream) {
  MArgs args;
  args.emb = (const float*)d_in[0];
  args.sa_in_w = (const float*)d_in[1];
  args.sa_in_b = (const float*)d_in[2];
  args.sa_out_w = (const float*)d_in[3];
  args.sa_out_b = (const float*)d_in[4];
  args.ca_in_w = (const float*)d_in[5];
  args.ca_in_b = (const float*)d_in[6];
  args.ca_out_w = (const float*)d_in[7];
  args.ca_out_b = (const float*)d_in[8];
  args.ff1_w = (const float*)d_in[9];
  args.ff1_b = (const float*)d_in[10];
  args.ff2_w = (const float*)d_in[11];
  args.ff2_b = (const float*)d_in[12];
  args.ln_w = (const float*)d_in[13];
  args.ln_b = (const float*)d_in[14];
  args.out_w = (const float*)d_in[15];
  args.out_b = (const float*)d_in[16];
  args.temp_w = (const float*)d_in[17];
  args.temp_b = (const float*)d_in[18];
  args.style_w = (const float*)d_in[21];
  args.style_b = (const float*)d_in[22];
  args.ws = (float*)d_ws;
  args.out = (float*)d_out;

  // Decide path deterministically from device properties + occupancy.
  int dev = 0;
  (void)hipGetDevice(&dev);
  int coop = 0;
  (void)hipDeviceGetAttribute(&coop, hipDeviceAttributeCooperativeLaunch, dev);
  int numCU = 0;
  (void)hipDeviceGetAttribute(&numCU, hipDeviceAttributeMultiprocessorCount,
                              dev);
  int maxblk = 0;
  hipError_t occ_err =
      hipOccupancyMaxActiveBlocksPerMultiprocessor(&maxblk, mega_kernel, 256, 0);

  hipError_t lerr = hipErrorUnknown;
  if (coop && occ_err == hipSuccess && maxblk >= 1 && numCU >= 2) {
    int blocks_per_cu = maxblk < 2 ? maxblk : 2;
    int grid = numCU * blocks_per_cu;
    void* params[] = {(void*)&args};
    lerr = hipLaunchCooperativeKernel(mega_kernel, dim3((unsigned)grid),
                                      dim3(256), params, 0, stream);
  }
  if (lerr != hipSuccess) {
    run_fallback(args, stream);  // proven multi-kernel schedule (round 5)
  }
}

// Round 9
// 11139.901 us; speedup vs baseline: 2.0412x; 2.0412x over previous
//
#include <hip/hip_runtime.h>
#include <stdint.h>

// ---------------- threefry2x32 (exact JAX schedule) ----------------
__host__ __device__ inline void threefry2x32(uint32_t k0, uint32_t k1,
                                             uint32_t x0, uint32_t x1,
                                             uint32_t* o0, uint32_t* o1) {
  uint32_t ks2 = 0x1BD11BDAu ^ k0 ^ k1;
  x0 += k0; x1 += k1;
#define TF_R(x, r) (((x) << (r)) | ((x) >> (32 - (r))))
#define TF_ROUND(r) { x0 += x1; x1 = TF_R(x1, r); x1 ^= x0; }
  TF_ROUND(13) TF_ROUND(15) TF_ROUND(26) TF_ROUND(6)
  x0 += k1; x1 += ks2 + 1u;
  TF_ROUND(17) TF_ROUND(29) TF_ROUND(16) TF_ROUND(24)
  x0 += ks2; x1 += k0 + 2u;
  TF_ROUND(13) TF_ROUND(15) TF_ROUND(26) TF_ROUND(6)
  x0 += k0; x1 += k1 + 3u;
  TF_ROUND(17) TF_ROUND(29) TF_ROUND(16) TF_ROUND(24)
  x0 += k1; x1 += ks2 + 4u;
  TF_ROUND(13) TF_ROUND(15) TF_ROUND(26) TF_ROUND(6)
  x0 += ks2; x1 += k0 + 5u;
  *o0 = x0; *o1 = x1;
#undef TF_ROUND
#undef TF_R
}

__device__ __forceinline__ float wave_sum(float v) {
#pragma unroll
  for (int o = 32; o > 0; o >>= 1) v += __shfl_xor(v, o, 64);
  return v;
}
__device__ __forceinline__ float wave_max(float v) {
#pragma unroll
  for (int o = 32; o > 0; o >>= 1) v = fmaxf(v, __shfl_xor(v, o, 64));
  return v;
}

// ============================================================================
// gemm3: split-K GEMM with fused atomic-flag reduction epilogue.
//   out = epilogue( LNx(X) @ W^T )
//   - X-side optional on-the-fly LayerNorm: xstats (mean,rstd per row),
//     xlnw/xlnb per column (K must be 1024 when used).
//   - Every block writes its K-split partial to Pp, fences, bumps tilecnt.
//     LAST block re-reads all partials IN FIXED ORDER (deterministic),
//     adds bias, optional residual (with optional on-the-fly LN), optional
//     relu, writes out.
//   - If ostats != null: per row-group (64 rows) the last finishing tile
//     computes row mean/rstd of `out` and writes ostats (deterministic:
//     single designated block, two-pass like the reference).
// X rows batch-mapped m -> (b=m/St, s=m%St).
// ============================================================================
__global__ __launch_bounds__(256) void gemm3_kernel(
    const float* __restrict__ X, long long xbs, int ldx,
    const float* __restrict__ xstats, const float* __restrict__ xlnw,
    const float* __restrict__ xlnb,
    const float* __restrict__ W, int ldw, const float* __restrict__ bias,
    const float* __restrict__ resY, long long rbs, int ldr,
    const float* __restrict__ rstats, const float* __restrict__ rlnw,
    const float* __restrict__ rlnb,
    float* __restrict__ Pp, float* __restrict__ out, long long obs, int ldo,
    float* __restrict__ ostats,
    int St, int M, int N, int K32, int relu,
    int* __restrict__ tilecnt, int* __restrict__ rowcnt) {
  __shared__ __align__(16) float Xl[2][32][68];
  __shared__ __align__(16) float Wl[2][32][68];
  __shared__ int sflag;
  const int tid = threadIdx.x;
  const int m0 = blockIdx.x * 64;
  const int n0 = blockIdx.y * 64;
  const int splits = gridDim.z;
  const int Nt = gridDim.y;
  const long long kbase = (long long)blockIdx.z * K32 * 32;
  const int mi = tid >> 4, ni = tid & 15, lr = tid >> 3, lc = (tid & 7) * 4;
  const int wid = tid >> 6, lane = tid & 63;

  const int mA = m0 + lr, mB = m0 + lr + 32;
  const float* xpA = nullptr;
  const float* xpB = nullptr;
  float mnA = 0.f, rsA = 1.f, mnB = 0.f, rsB = 1.f;
  if (mA < M) {
    int b = mA / St, s = mA - b * St;
    xpA = X + (long long)b * xbs + (long long)s * ldx + kbase + lc;
    if (xstats) { mnA = xstats[2 * mA]; rsA = xstats[2 * mA + 1]; }
  }
  if (mB < M) {
    int b = mB / St, s = mB - b * St;
    xpB = X + (long long)b * xbs + (long long)s * ldx + kbase + lc;
    if (xstats) { mnB = xstats[2 * mB]; rsB = xstats[2 * mB + 1]; }
  }
  const float* wpA = W + (long long)(n0 + lr) * ldw + kbase + lc;
  const float* wpB = W + (long long)(n0 + lr + 32) * ldw + kbase + lc;
  const float* lwp = xlnw ? xlnw + kbase + lc : nullptr;
  const float* lbp = xlnb ? xlnb + kbase + lc : nullptr;

  float4 xA = xpA ? *(const float4*)xpA : make_float4(0.f, 0.f, 0.f, 0.f);
  float4 xB = xpB ? *(const float4*)xpB : make_float4(0.f, 0.f, 0.f, 0.f);
  float4 wA = *(const float4*)wpA;
  float4 wB = *(const float4*)wpB;
  float4 lw4 = make_float4(1.f, 1.f, 1.f, 1.f);
  float4 lb4 = make_float4(0.f, 0.f, 0.f, 0.f);
  if (lwp) { lw4 = *(const float4*)lwp; lb4 = *(const float4*)lbp; }

  float acc[4][4];
#pragma unroll
  for (int i = 0; i < 4; ++i)
#pragma unroll
    for (int j = 0; j < 4; ++j) acc[i][j] = 0.f;

  // apply X-side LN to chunk 0 (garbage rows m>=M are never consumed)
  if (xstats) {
    xA.x = (xA.x - mnA) * rsA * lw4.x + lb4.x;
    xA.y = (xA.y - mnA) * rsA * lw4.y + lb4.y;
    xA.z = (xA.z - mnA) * rsA * lw4.z + lb4.z;
    xA.w = (xA.w - mnA) * rsA * lw4.w + lb4.w;
    xB.x = (xB.x - mnB) * rsB * lw4.x + lb4.x;
    xB.y = (xB.y - mnB) * rsB * lw4.y + lb4.y;
    xB.z = (xB.z - mnB) * rsB * lw4.z + lb4.z;
    xB.w = (xB.w - mnB) * rsB * lw4.w + lb4.w;
  }

  Xl[0][lc + 0][lr] = xA.x; Xl[0][lc + 1][lr] = xA.y;
  Xl[0][lc + 2][lr] = xA.z; Xl[0][lc + 3][lr] = xA.w;
  Xl[0][lc + 0][lr + 32] = xB.x; Xl[0][lc + 1][lr + 32] = xB.y;
  Xl[0][lc + 2][lr + 32] = xB.z; Xl[0][lc + 3][lr + 32] = xB.w;
  Wl[0][lc + 0][lr] = wA.x; Wl[0][lc + 1][lr] = wA.y;
  Wl[0][lc + 2][lr] = wA.z; Wl[0][lc + 3][lr] = wA.w;
  Wl[0][lc + 0][lr + 32] = wB.x; Wl[0][lc + 1][lr + 32] = wB.y;
  Wl[0][lc + 2][lr + 32] = wB.z; Wl[0][lc + 3][lr + 32] = wB.w;
  __syncthreads();

  for (int i = 0; i < K32; ++i) {
    if (i + 1 < K32) {  // prefetch next tile (raw) before compute
      int off = (i + 1) * 32;
      xA = xpA ? *(const float4*)(xpA + off) : make_float4(0.f, 0.f, 0.f, 0.f);
      xB = xpB ? *(const float4*)(xpB + off) : make_float4(0.f, 0.f, 0.f, 0.f);
      wA = *(const float4*)(wpA + off);
      wB = *(const float4*)(wpB + off);
      if (lwp) {
        lw4 = *(const float4*)(lwp + off);
        lb4 = *(const float4*)(lbp + off);
      }
    }
    const int cur = i & 1;
#pragma unroll
    for (int kk = 0; kk < 32; ++kk) {
      float4 xv = *(const float4*)&Xl[cur][kk][mi * 4];
      float4 wv = *(const float4*)&Wl[cur][kk][ni * 4];
      float xa[4] = {xv.x, xv.y, xv.z, xv.w};
      float wa[4] = {wv.x, wv.y, wv.z, wv.w};
#pragma unroll
      for (int a2 = 0; a2 < 4; ++a2)
#pragma unroll
        for (int c2 = 0; c2 < 4; ++c2)
          acc[a2][c2] = fmaf(xa[a2], wa[c2], acc[a2][c2]);
    }
    if (i + 1 < K32) {
      if (xstats) {
        xA.x = (xA.x - mnA) * rsA * lw4.x + lb4.x;
        xA.y = (xA.y - mnA) * rsA * lw4.y + lb4.y;
        xA.z = (xA.z - mnA) * rsA * lw4.z + lb4.z;
        xA.w = (xA.w - mnA) * rsA * lw4.w + lb4.w;
        xB.x = (xB.x - mnB) * rsB * lw4.x + lb4.x;
        xB.y = (xB.y - mnB) * rsB * lw4.y + lb4.y;
        xB.z = (xB.z - mnB) * rsB * lw4.z + lb4.z;
        xB.w = (xB.w - mnB) * rsB * lw4.w + lb4.w;
      }
      __syncthreads();
      const int nxt = cur ^ 1;
      Xl[nxt][lc + 0][lr] = xA.x; Xl[nxt][lc + 1][lr] = xA.y;
      Xl[nxt][lc + 2][lr] = xA.z; Xl[nxt][lc + 3][lr] = xA.w;
      Xl[nxt][lc + 0][lr + 32] = xB.x; Xl[nxt][lc + 1][lr + 32] = xB.y;
      Xl[nxt][lc + 2][lr + 32] = xB.z; Xl[nxt][lc + 3][lr + 32] = xB.w;
      Wl[nxt][lc + 0][lr] = wA.x; Wl[nxt][lc + 1][lr] = wA.y;
      Wl[nxt][lc + 2][lr] = wA.z; Wl[nxt][lc + 3][lr] = wA.w;
      Wl[nxt][lc + 0][lr + 32] = wB.x; Wl[nxt][lc + 1][lr + 32] = wB.y;
      Wl[nxt][lc + 2][lr + 32] = wB.z; Wl[nxt][lc + 3][lr + 32] = wB.w;
      __syncthreads();
    }
  }

  const int n = n0 + ni * 4;
  // ---- write this split's partial ----
  {
    float* base = Pp + (long long)blockIdx.z * M * N;
#pragma unroll
    for (int i = 0; i < 4; ++i) {
      int m = m0 + mi * 4 + i;
      if (m >= M) continue;
      *(float4*)(base + (long long)m * N + n) =
          make_float4(acc[i][0], acc[i][1], acc[i][2], acc[i][3]);
    }
  }
  __threadfence();   // release: partial visible device-wide
  __syncthreads();
  if (tid == 0)
    sflag = (atomicAdd(tilecnt + blockIdx.y * gridDim.x + blockIdx.x, 1) ==
             splits - 1);
  __syncthreads();
  if (!sflag) return;   // uniform
  __threadfence();      // acquire

  // ---- last block: reduce partials (fixed order) + epilogue ----
  float4 bv = *(const float4*)(bias + n);
#pragma unroll
  for (int i = 0; i < 4; ++i) {
    int m = m0 + mi * 4 + i;
    if (m >= M) continue;
    float4 v = make_float4(0.f, 0.f, 0.f, 0.f);
    for (int sp = 0; sp < splits; ++sp) {
      float4 p = *(const float4*)(Pp + (long long)sp * M * N +
                                  (long long)m * N + n);
      v.x += p.x; v.y += p.y; v.z += p.z; v.w += p.w;
    }
    v.x += bv.x; v.y += bv.y; v.z += bv.z; v.w += bv.w;
    int b = m / St, s = m - b * St;
    if (resY) {
      float4 rv =
          *(const float4*)(resY + (long long)b * rbs + (long long)s * ldr + n);
      if (rstats) {
        float rm = rstats[2 * m], rr = rstats[2 * m + 1];
        float4 rw = *(const float4*)(rlnw + n);
        float4 rb2 = *(const float4*)(rlnb + n);
        rv.x = (rv.x - rm) * rr * rw.x + rb2.x;
        rv.y = (rv.y - rm) * rr * rw.y + rb2.y;
        rv.z = (rv.z - rm) * rr * rw.z + rb2.z;
        rv.w = (rv.w - rm) * rr * rw.w + rb2.w;
      }
      v.x += rv.x; v.y += rv.y; v.z += rv.z; v.w += rv.w;
    }
    if (relu) {
      v.x = fmaxf(v.x, 0.f); v.y = fmaxf(v.y, 0.f);
      v.z = fmaxf(v.z, 0.f); v.w = fmaxf(v.w, 0.f);
    }
    *(float4*)(out + (long long)b * obs + (long long)s * ldo + n) = v;
  }

  // ---- optional: last tile in row-group computes LN stats of out ----
  if (ostats) {
    __threadfence();
    __syncthreads();
    if (tid == 0)
      sflag = (atomicAdd(rowcnt + blockIdx.x, 1) == Nt - 1);
    __syncthreads();
    if (!sflag) return;  // uniform
    __threadfence();
    for (int r = wid; r < 64; r += 4) {
      int m = m0 + r;
      if (m >= M) continue;
      int b = m / St, s = m - b * St;
      const float* row = out + (long long)b * obs + (long long)s * ldo;
      float sm = 0.f;
#pragma unroll
      for (int it = 0; it < 4; ++it) {
        float4 xv = *(const float4*)(row + it * 256 + lane * 4);
        sm += xv.x + xv.y + xv.z + xv.w;
      }
      sm = wave_sum(sm) * (1.f / 1024.f);
      float s2 = 0.f;
#pragma unroll
      for (int it = 0; it < 4; ++it) {
        float4 xv = *(const float4*)(row + it * 256 + lane * 4);
        float dx = xv.x - sm, dy = xv.y - sm, dz = xv.z - sm, dw = xv.w - sm;
        s2 += dx * dx + dy * dy + dz * dz + dw * dw;
      }
      s2 = wave_sum(s2) * (1.f / 1024.f);
      if (lane == 0) {
        ostats[2 * m] = sm;
        ostats[2 * m + 1] = rsqrtf(s2 + 1e-5f);
      }
    }
  }
}

// ---------------- attention: one wave per (b, h, sq) ----------------
__global__ __launch_bounds__(64) void attn_kernel(
    const float* __restrict__ Qp, int q_rs, long long q_bs,
    const float* __restrict__ Kp, int k_rs, long long k_bs,
    const float* __restrict__ Vp, int v_rs, long long v_bs,
    float* __restrict__ Op, int o_rs, long long o_bs,
    int Sq, int Skv) {
  const int lane = threadIdx.x;
  int bid = blockIdx.x;
  int b = bid / (8 * Sq);
  int rr = bid - b * 8 * Sq;
  int h = rr / Sq;
  int sq = rr - h * Sq;
  const float* qrow = Qp + (long long)b * q_bs + (long long)sq * q_rs + h * 128;
  float q0 = qrow[lane], q1 = qrow[lane + 64];
  __shared__ float sc[72];
  const float* kb = Kp + (long long)b * k_bs + h * 128;
  for (int sk = 0; sk < Skv; ++sk) {
    const float* kr = kb + (long long)sk * k_rs;
    float p = fmaf(q0, kr[lane], q1 * kr[lane + 64]);
    p = wave_sum(p);
    if (lane == 0) sc[sk] = p * 0.08838834764831845f;  // 1/sqrt(128)
  }
  __syncthreads();
  float m = -3.4e38f;
  for (int i = lane; i < Skv; i += 64) m = fmaxf(m, sc[i]);
  m = wave_max(m);
  float ssum = 0.f;
  for (int i = lane; i < Skv; i += 64) {
    float e = expf(sc[i] - m);
    sc[i] = e;
    ssum += e;
  }
  ssum = wave_sum(ssum);
  __syncthreads();
  float o0 = 0.f, o1 = 0.f;
  const float* vb = Vp + (long long)b * v_bs + h * 128;
  for (int sk = 0; sk < Skv; ++sk) {
    float w = sc[sk];
    const float* vr = vb + (long long)sk * v_rs;
    o0 = fmaf(w, vr[lane], o0);
    o1 = fmaf(w, vr[lane + 64], o1);
  }
  float inv = 1.f / ssum;
  float* orow = Op + (long long)b * o_bs + (long long)sq * o_rs + h * 128;
  orow[lane] = o0 * inv;
  orow[lane + 64] = o1 * inv;
}

// ---------------- small preprocessing kernels ----------------
__global__ __launch_bounds__(256) void copy_cur_kernel(
    const float* __restrict__ emb, float* __restrict__ cur) {
  int idx = blockIdx.x * 256 + threadIdx.x;
  int b = idx >> 16;
  int r = idx & 65535;
  cur[(long long)b * 73728 + r] = emb[idx];
}

__global__ __launch_bounds__(256) void xmean_kernel(
    const float* __restrict__ emb, float* __restrict__ xmean) {
  int idx = blockIdx.x * 256 + threadIdx.x;
  int b = idx >> 10, d = idx & 1023;
  float s = 0.f;
  for (int ss = 0; ss < 64; ++ss) s += emb[b * 65536 + ss * 1024 + d];
  xmean[idx] = s * (1.f / 64.f);
}

__global__ __launch_bounds__(256) void temp_kernel(
    const float* __restrict__ emb, const float* __restrict__ tw,
    const float* __restrict__ tb, float* __restrict__ tempv) {
  __shared__ float red[4];
  int b = blockIdx.x;
  int wid = threadIdx.x >> 6, lane = threadIdx.x & 63;
  float acc = 0.f;
  for (int s = wid; s < 64; s += 4) {
    const float* x = emb + b * 65536 + s * 1024;
    float p = 0.f;
#pragma unroll
    for (int it = 0; it < 4; ++it) {
      float4 xv = *(const float4*)(x + it * 256 + lane * 4);
      float4 wv = *(const float4*)(tw + it * 256 + lane * 4);
      p += xv.x * wv.x + xv.y * wv.y + xv.z * wv.z + xv.w * wv.w;
    }
    p = wave_sum(p);
    acc += 1.f / (1.f + expf(-(p + tb[0])));
  }
  if (lane == 0) red[wid] = acc;
  __syncthreads();
  if (threadIdx.x == 0)
    tempv[b] = (red[0] + red[1] + red[2] + red[3]) * (1.f / 64.f);
}

__global__ __launch_bounds__(256) void style_kernel(
    const float* __restrict__ xmean, const float* __restrict__ sw,
    const float* __restrict__ sb, float* __restrict__ stylev) {
  int wid = threadIdx.x >> 6, lane = threadIdx.x & 63;
  int d = blockIdx.x * 4 + wid;
  const float* wr = sw + (long long)d * 1024;
  float a0 = 0.f, a1 = 0.f;
#pragma unroll
  for (int it = 0; it < 4; ++it) {
    float4 wv = *(const float4*)(wr + it * 256 + lane * 4);
    float4 x0 = *(const float4*)(xmean + it * 256 + lane * 4);
    float4 x1 = *(const float4*)(xmean + 1024 + it * 256 + lane * 4);
    a0 += wv.x * x0.x + wv.y * x0.y + wv.z * x0.z + wv.w * x0.w;
    a1 += wv.x * x1.x + wv.y * x1.y + wv.z * x1.z + wv.w * x1.w;
  }
  a0 = wave_sum(a0);
  a1 = wave_sum(a1);
  if (lane == 0) {
    stylev[d] = a0 + sb[d];
    stylev[1024 + d] = a1 + sb[d];
  }
}

// -------- logits: z = LN(Y[:,St-1]) + style, one wave per vocab row --------
__global__ __launch_bounds__(256) void logits_kernel(
    const float* __restrict__ Y, const float* __restrict__ ystats,
    const float* __restrict__ lnw, const float* __restrict__ lnb, int St,
    const float* __restrict__ stylev, const float* __restrict__ Wo,
    const float* __restrict__ bo, const float* __restrict__ tempv,
    float* __restrict__ outl, int t) {
  int wid = threadIdx.x >> 6, lane = threadIdx.x & 63;
  int n = blockIdx.x * 4 + wid;
  const float* wr = Wo + (long long)n * 1024;
  int m0 = St - 1, m1 = St + St - 1;
  const float* y0 = Y + (long long)(St - 1) * 1024;
  const float* y1 = Y + 73728 + (long long)(St - 1) * 1024;
  float mean0 = ystats[2 * m0], rstd0 = ystats[2 * m0 + 1];
  float mean1 = ystats[2 * m1], rstd1 = ystats[2 * m1 + 1];
  float a0 = 0.f, a1 = 0.f;
#pragma unroll
  for (int it = 0; it < 4; ++it) {
    int off = it * 256 + lane * 4;
    float4 wv = *(const float4*)(wr + off);
    float4 lw = *(const float4*)(lnw + off);
    float4 lb = *(const float4*)(lnb + off);
    float4 s0 = *(const float4*)(stylev + off);
    float4 s1 = *(const float4*)(stylev + 1024 + off);
    float4 x0 = *(const float4*)(y0 + off);
    float4 x1 = *(const float4*)(y1 + off);
    float z0x = (x0.x - mean0) * rstd0 * lw.x + lb.x + s0.x;
    float z0y = (x0.y - mean0) * rstd0 * lw.y + lb.y + s0.y;
    float z0z = (x0.z - mean0) * rstd0 * lw.z + lb.z + s0.z;
    float z0w = (x0.w - mean0) * rstd0 * lw.w + lb.w + s0.w;
    float z1x = (x1.x - mean1) * rstd1 * lw.x + lb.x + s1.x;
    float z1y = (x1.y - mean1) * rstd1 * lw.y + lb.y + s1.y;
    float z1z = (x1.z - mean1) * rstd1 * lw.z + lb.z + s1.z;
    float z1w = (x1.w - mean1) * rstd1 * lw.w + lb.w + s1.w;
    a0 += wv.x * z0x + wv.y * z0y + wv.z * z0z + wv.w * z0w;
    a1 += wv.x * z1x + wv.y * z1y + wv.z * z1z + wv.w * z1w;
  }
  a0 = wave_sum(a0);
  a1 = wave_sum(a1);
  if (lane == 0) {
    float bb = bo[n];
    outl[(long long)(0 * 8 + t) * 32000 + n] = (a0 + bb) / tempv[0];
    outl[(long long)(1 * 8 + t) * 32000 + n] = (a1 + bb) / tempv[1];
  }
}

// -------- Gumbel argmax sampling (exact partitionable threefry) + append ----
__global__ __launch_bounds__(1024) void sample_kernel(
    const float* __restrict__ logits, const float* __restrict__ Wo,
    float* __restrict__ tok_f, float* __restrict__ cur, int St,
    uint32_t fk0, uint32_t fk1, int t) {
  int b = blockIdx.x;
  const float* lg = logits + (long long)(b * 8 + t) * 32000;
  float best = -3.4e38f;
  int bi = 0x7fffffff;
  for (int n = threadIdx.x; n < 32000; n += 1024) {
    uint32_t r0, r1;
    threefry2x32(fk0, fk1, 0u, (uint32_t)(b * 32000 + n), &r0, &r1);
    uint32_t bits = (r0 ^ r1) >> 9;
    float u = __uint_as_float(0x3f800000u | bits) - 1.0f;
    if (u < 1.1754944e-38f) u = 1.1754944e-38f;
    float g = -logf(-logf(u));
    float val = lg[n] + g;
    if (val > best) { best = val; bi = n; }
  }
  __shared__ float bv[1024];
  __shared__ int bix[1024];
  bv[threadIdx.x] = best;
  bix[threadIdx.x] = bi;
  __syncthreads();
  for (int s = 512; s > 0; s >>= 1) {
    if (threadIdx.x < s) {
      float ov = bv[threadIdx.x + s];
      int oi = bix[threadIdx.x + s];
      if (ov > bv[threadIdx.x] ||
          (ov == bv[threadIdx.x] && oi < bix[threadIdx.x])) {
        bv[threadIdx.x] = ov;
        bix[threadIdx.x] = oi;
      }
    }
    __syncthreads();
  }
  int tok = bix[0];
  if (threadIdx.x == 0) tok_f[b * 8 + t] = (float)tok;
  cur[(long long)b * 73728 + (long long)St * 1024 + threadIdx.x] =
      Wo[(long long)tok * 1024 + threadIdx.x];
}

// ============================================================================
extern "C" void kernel_launch(void* const* d_in, const int* in_sizes, int n_in,
                              void* d_out, int out_size, void* d_ws,
                              size_t ws_size, hipStream_t stream) {
  const float* emb = (const float*)d_in[0];
  const float* sa_in_w = (const float*)d_in[1];
  const float* sa_in_b = (const float*)d_in[2];
  const float* sa_out_w = (const float*)d_in[3];
  const float* sa_out_b = (const float*)d_in[4];
  const float* ca_in_w = (const float*)d_in[5];
  const float* ca_in_b = (const float*)d_in[6];
  const float* ca_out_w = (const float*)d_in[7];
  const float* ca_out_b = (const float*)d_in[8];
  const float* ff1_w = (const float*)d_in[9];
  const float* ff1_b = (const float*)d_in[10];
  const float* ff2_w = (const float*)d_in[11];
  const float* ff2_b = (const float*)d_in[12];
  const float* ln_w = (const float*)d_in[13];
  const float* ln_b = (const float*)d_in[14];
  const float* out_w = (const float*)d_in[15];
  const float* out_b = (const float*)d_in[16];
  const float* temp_w = (const float*)d_in[17];
  const float* temp_b = (const float*)d_in[18];
  const float* style_w = (const float*)d_in[21];
  const float* style_b = (const float*)d_in[22];

  float* ws = (float*)d_ws;
  float* cur = ws;                          // [2][72][1024]
  float* Qb = cur + 147456;                 // [2][72][3072]
  float* Tb = Qb + 442368;                  // [2][72][1024]
  float* T2 = Tb + 147456;                  // [2][72][1024]
  float* Fb = T2 + 147456;                  // [2][72][4096]
  float* Yb = Fb + 589824;                  // 6 x [2][72][1024]
  float* cakv = Yb + 884736;                // [2][2][64][2048]
  float* Pp = cakv + 524288;                // split-K partials (2.4M floats)
  float* xmean = Pp + 2400000;              // 2048
  float* stylev = xmean + 2048;             // 2048
  float* tempv = stylev + 2048;             // 16
  float* statsb = tempv + 16;               // 6 x 288
  int* cntpool = (int*)(statsb + 1728);     // 100 x 256 ints

  float* toks_out = (float*)d_out;
  float* logits_out = toks_out + 16;

  auto Y = [&](int l, int j) { return Yb + (size_t)(l * 3 + j) * 147456; };
  auto SS = [&](int l, int j) { return statsb + (size_t)(l * 3 + j) * 288; };

  // zero the atomic-counter pool (re-zeroed each replay as a graph node)
  hipMemsetAsync(cntpool, 0, 100 * 256 * sizeof(int), stream);

  int inst = 0;
  auto g3 = [&](const float* X, long long xbs, int ldx, const float* xst,
                const float* xlw, const float* xlb, const float* W, int ldw,
                const float* bias, const float* resY, long long rbs, int ldr,
                const float* rst, const float* rlw, const float* rlb,
                float* out, long long obs, int ldo, float* ost, int St, int M,
                int N, int K, int splits, int relu) {
    dim3 grid((unsigned)((M + 63) / 64), (unsigned)(N / 64),
              (unsigned)splits);
    int* tc = cntpool + inst * 256;
    ++inst;
    gemm3_kernel<<<grid, 256, 0, stream>>>(
        X, xbs, ldx, xst, xlw, xlb, W, ldw, bias, resY, rbs, ldr, rst, rlw,
        rlb, Pp, out, obs, ldo, ost, St, M, N, K / (32 * splits), relu, tc,
        tc + 200);
  };

  // ---- precompute ----
  copy_cur_kernel<<<512, 256, 0, stream>>>(emb, cur);
  xmean_kernel<<<8, 256, 0, stream>>>(emb, xmean);
  temp_kernel<<<2, 256, 0, stream>>>(emb, temp_w, temp_b, tempv);
  style_kernel<<<256, 256, 0, stream>>>(xmean, style_w, style_b, stylev);
  for (int l = 0; l < 2; ++l)  // cross-attn K,V from constant memory input
    g3(emb, 64 * 1024, 1024, nullptr, nullptr, nullptr,
       ca_in_w + (size_t)(l * 3072 + 1024) * 1024, 1024,
       ca_in_b + l * 3072 + 1024, nullptr, 0, 0, nullptr, nullptr, nullptr,
       cakv + (size_t)l * 2 * 64 * 2048, 64 * 2048, 2048, nullptr, 64, 128,
       2048, 1024, 4, 0);

  for (int t = 0; t < 8; ++t) {
    const int St = 64 + t;
    const int M = 2 * St;
    for (int l = 0; l < 2; ++l) {
      // X0 descriptor: layer0 -> cur (raw); layer1 -> LN(Y2 of layer0)
      const float* X0 = (l == 0) ? cur : Y(0, 2);
      const float* X0st = (l == 0) ? nullptr : SS(0, 2);
      const float* X0lw = (l == 0) ? nullptr : ln_w + (0 * 3 + 2) * 1024;
      const float* X0lb = (l == 0) ? nullptr : ln_b + (0 * 3 + 2) * 1024;

      // 1) self-attn QKV (fused bias) -> Qb
      g3(X0, 72 * 1024, 1024, X0st, X0lw, X0lb,
         sa_in_w + (size_t)l * 3072 * 1024, 1024, sa_in_b + l * 3072, nullptr,
         0, 0, nullptr, nullptr, nullptr, Qb, 72 * 3072, 3072, nullptr, St, M,
         3072, 1024, 4, 0);
      // 2) self-attention
      attn_kernel<<<2 * 8 * St, 64, 0, stream>>>(
          Qb, 3072, 72 * 3072, Qb + 1024, 3072, 72 * 3072, Qb + 2048, 3072,
          72 * 3072, Tb, 1024, 72 * 1024, St, St);
      // 3) out-proj + bias + residual(X0,LN) -> Y0 raw, stats0
      g3(Tb, 72 * 1024, 1024, nullptr, nullptr, nullptr,
         sa_out_w + (size_t)l * 1024 * 1024, 1024, sa_out_b + l * 1024, X0,
         72 * 1024, 1024, X0st, X0lw, X0lb, Y(l, 0), 72 * 1024, 1024,
         SS(l, 0), St, M, 1024, 1024, 8, 0);
      // 4) cross-attn Q = LN(Y0) @ Wq + bq -> T2
      g3(Y(l, 0), 72 * 1024, 1024, SS(l, 0), ln_w + (l * 3 + 0) * 1024,
         ln_b + (l * 3 + 0) * 1024, ca_in_w + (size_t)l * 3072 * 1024, 1024,
         ca_in_b + l * 3072, nullptr, 0, 0, nullptr, nullptr, nullptr, T2,
         72 * 1024, 1024, nullptr, St, M, 1024, 1024, 8, 0);
      // 5) cross-attention
      attn_kernel<<<2 * 8 * St, 64, 0, stream>>>(
          T2, 1024, 72 * 1024, cakv + (size_t)l * 2 * 64 * 2048, 2048,
          64 * 2048, cakv + (size_t)l * 2 * 64 * 2048 + 1024, 2048, 64 * 2048,
          Tb, 1024, 72 * 1024, St, 64);
      // 6) ca out-proj + bias + residual(LN(Y0)) -> Y1 raw, stats1
      g3(Tb, 72 * 1024, 1024, nullptr, nullptr, nullptr,
         ca_out_w + (size_t)l * 1024 * 1024, 1024, ca_out_b + l * 1024,
         Y(l, 0), 72 * 1024, 1024, SS(l, 0), ln_w + (l * 3 + 0) * 1024,
         ln_b + (l * 3 + 0) * 1024, Y(l, 1), 72 * 1024, 1024, SS(l, 1), St, M,
         1024, 1024, 8, 0);
      // 7) FFN1: relu(LN(Y1) @ W1 + b1) -> Fb
      g3(Y(l, 1), 72 * 1024, 1024, SS(l, 1), ln_w + (l * 3 + 1) * 1024,
         ln_b + (l * 3 + 1) * 1024, ff1_w + (size_t)l * 4096 * 1024, 1024,
         ff1_b + l * 4096, nullptr, 0, 0, nullptr, nullptr, nullptr, Fb,
         72 * 4096, 4096, nullptr, St, M, 4096, 1024, 4, 1);
      // 8) FFN2: Fb @ W2 + b2 + residual(LN(Y1)) -> Y2 raw, stats2
      g3(Fb, 72 * 4096, 4096, nullptr, nullptr, nullptr,
         ff2_w + (size_t)l * 1024 * 4096, 4096, ff2_b + l * 1024, Y(l, 1),
         72 * 1024, 1024, SS(l, 1), ln_w + (l * 3 + 1) * 1024,
         ln_b + (l * 3 + 1) * 1024, Y(l, 2), 72 * 1024, 1024, SS(l, 2), St, M,
         1024, 4096, 16, 0);
    }
    // logits from LN(Y2 of layer 1) + style
    logits_kernel<<<8000, 256, 0, stream>>>(
        Y(1, 2), SS(1, 2), ln_w + (1 * 3 + 2) * 1024,
        ln_b + (1 * 3 + 2) * 1024, St, stylev, out_w, out_b, tempv,
        logits_out, t);
    uint32_t fk0, fk1;
    threefry2x32(0u, 42u, 0u, (uint32_t)t, &fk0, &fk1);
    sample_kernel<<<2, 1024, 0, stream>>>(logits_out, out_w, toks_out, cur,
                                          St, fk0, fk1, t);
  }
}

// Round 10
// 7295.716 us; speedup vs baseline: 3.1168x; 1.5269x over previous
//
#include <hip/hip_runtime.h>
#include <stdint.h>

// ---------------- threefry2x32 (exact JAX schedule) ----------------
__host__ __device__ inline void threefry2x32(uint32_t k0, uint32_t k1,
                                             uint32_t x0, uint32_t x1,
                                             uint32_t* o0, uint32_t* o1) {
  uint32_t ks2 = 0x1BD11BDAu ^ k0 ^ k1;
  x0 += k0; x1 += k1;
#define TF_R(x, r) (((x) << (r)) | ((x) >> (32 - (r))))
#define TF_ROUND(r) { x0 += x1; x1 = TF_R(x1, r); x1 ^= x0; }
  TF_ROUND(13) TF_ROUND(15) TF_ROUND(26) TF_ROUND(6)
  x0 += k1; x1 += ks2 + 1u;
  TF_ROUND(17) TF_ROUND(29) TF_ROUND(16) TF_ROUND(24)
  x0 += ks2; x1 += k0 + 2u;
  TF_ROUND(13) TF_ROUND(15) TF_ROUND(26) TF_ROUND(6)
  x0 += k0; x1 += k1 + 3u;
  TF_ROUND(17) TF_ROUND(29) TF_ROUND(16) TF_ROUND(24)
  x0 += k1; x1 += ks2 + 4u;
  TF_ROUND(13) TF_ROUND(15) TF_ROUND(26) TF_ROUND(6)
  x0 += ks2; x1 += k0 + 5u;
  *o0 = x0; *o1 = x1;
#undef TF_ROUND
#undef TF_R
}

__device__ __forceinline__ float wave_sum(float v) {
#pragma unroll
  for (int o = 32; o > 0; o >>= 1) v += __shfl_xor(v, o, 64);
  return v;
}
__device__ __forceinline__ float wave_max(float v) {
#pragma unroll
  for (int o = 32; o > 0; o >>= 1) v = fmaxf(v, __shfl_xor(v, o, 64));
  return v;
}

// Agent-coherent (sc1, L2-bypassing) scalar ops — NO cache-flush fences.
__device__ __forceinline__ void agent_store(float* p, float v) {
  __hip_atomic_store(p, v, __ATOMIC_RELAXED, __HIP_MEMORY_SCOPE_AGENT);
}
__device__ __forceinline__ float agent_load(const float* p) {
  return __hip_atomic_load(p, __ATOMIC_RELAXED, __HIP_MEMORY_SCOPE_AGENT);
}

// ============================================================================
// gemm3: split-K GEMM with fence-free fused reduction epilogue.
//   Partials written with agent-scope coherent stores (bypass non-coherent
//   XCD L2 -> land in Infinity Cache). After vmcnt(0)+barrier, one relaxed
//   agent-scope atomicAdd elects the LAST block per tile, which re-reads all
//   partials IN FIXED ORDER (deterministic), adds bias / residual(+LN) /
//   relu, writes out (coherent stores when row-stats are needed), and the
//   last tile per row-group computes LN stats of the output rows.
// X rows batch-mapped m -> (b=m/St, s=m%St). Optional on-the-fly X-side LN.
// ============================================================================
__global__ __launch_bounds__(256) void gemm3_kernel(
    const float* __restrict__ X, long long xbs, int ldx,
    const float* __restrict__ xstats, const float* __restrict__ xlnw,
    const float* __restrict__ xlnb,
    const float* __restrict__ W, int ldw, const float* __restrict__ bias,
    const float* __restrict__ resY, long long rbs, int ldr,
    const float* __restrict__ rstats, const float* __restrict__ rlnw,
    const float* __restrict__ rlnb,
    float* __restrict__ Pp, float* __restrict__ out, long long obs, int ldo,
    float* __restrict__ ostats,
    int St, int M, int N, int K32, int relu,
    int* __restrict__ tilecnt, int* __restrict__ rowcnt) {
  __shared__ __align__(16) float Xl[2][32][68];
  __shared__ __align__(16) float Wl[2][32][68];
  __shared__ int sflag;
  const int tid = threadIdx.x;
  const int m0 = blockIdx.x * 64;
  const int n0 = blockIdx.y * 64;
  const int splits = gridDim.z;
  const int Nt = gridDim.y;
  const long long kbase = (long long)blockIdx.z * K32 * 32;
  const int mi = tid >> 4, ni = tid & 15, lr = tid >> 3, lc = (tid & 7) * 4;
  const int wid = tid >> 6, lane = tid & 63;

  const int mA = m0 + lr, mB = m0 + lr + 32;
  const float* xpA = nullptr;
  const float* xpB = nullptr;
  float mnA = 0.f, rsA = 1.f, mnB = 0.f, rsB = 1.f;
  if (mA < M) {
    int b = mA / St, s = mA - b * St;
    xpA = X + (long long)b * xbs + (long long)s * ldx + kbase + lc;
    if (xstats) { mnA = xstats[2 * mA]; rsA = xstats[2 * mA + 1]; }
  }
  if (mB < M) {
    int b = mB / St, s = mB - b * St;
    xpB = X + (long long)b * xbs + (long long)s * ldx + kbase + lc;
    if (xstats) { mnB = xstats[2 * mB]; rsB = xstats[2 * mB + 1]; }
  }
  const float* wpA = W + (long long)(n0 + lr) * ldw + kbase + lc;
  const float* wpB = W + (long long)(n0 + lr + 32) * ldw + kbase + lc;
  const float* lwp = xlnw ? xlnw + kbase + lc : nullptr;
  const float* lbp = xlnb ? xlnb + kbase + lc : nullptr;

  float4 xA = xpA ? *(const float4*)xpA : make_float4(0.f, 0.f, 0.f, 0.f);
  float4 xB = xpB ? *(const float4*)xpB : make_float4(0.f, 0.f, 0.f, 0.f);
  float4 wA = *(const float4*)wpA;
  float4 wB = *(const float4*)wpB;
  float4 lw4 = make_float4(1.f, 1.f, 1.f, 1.f);
  float4 lb4 = make_float4(0.f, 0.f, 0.f, 0.f);
  if (lwp) { lw4 = *(const float4*)lwp; lb4 = *(const float4*)lbp; }

  float acc[4][4];
#pragma unroll
  for (int i = 0; i < 4; ++i)
#pragma unroll
    for (int j = 0; j < 4; ++j) acc[i][j] = 0.f;

  if (xstats) {
    xA.x = (xA.x - mnA) * rsA * lw4.x + lb4.x;
    xA.y = (xA.y - mnA) * rsA * lw4.y + lb4.y;
    xA.z = (xA.z - mnA) * rsA * lw4.z + lb4.z;
    xA.w = (xA.w - mnA) * rsA * lw4.w + lb4.w;
    xB.x = (xB.x - mnB) * rsB * lw4.x + lb4.x;
    xB.y = (xB.y - mnB) * rsB * lw4.y + lb4.y;
    xB.z = (xB.z - mnB) * rsB * lw4.z + lb4.z;
    xB.w = (xB.w - mnB) * rsB * lw4.w + lb4.w;
  }

  Xl[0][lc + 0][lr] = xA.x; Xl[0][lc + 1][lr] = xA.y;
  Xl[0][lc + 2][lr] = xA.z; Xl[0][lc + 3][lr] = xA.w;
  Xl[0][lc + 0][lr + 32] = xB.x; Xl[0][lc + 1][lr + 32] = xB.y;
  Xl[0][lc + 2][lr + 32] = xB.z; Xl[0][lc + 3][lr + 32] = xB.w;
  Wl[0][lc + 0][lr] = wA.x; Wl[0][lc + 1][lr] = wA.y;
  Wl[0][lc + 2][lr] = wA.z; Wl[0][lc + 3][lr] = wA.w;
  Wl[0][lc + 0][lr + 32] = wB.x; Wl[0][lc + 1][lr + 32] = wB.y;
  Wl[0][lc + 2][lr + 32] = wB.z; Wl[0][lc + 3][lr + 32] = wB.w;
  __syncthreads();

  for (int i = 0; i < K32; ++i) {
    if (i + 1 < K32) {
      int off = (i + 1) * 32;
      xA = xpA ? *(const float4*)(xpA + off) : make_float4(0.f, 0.f, 0.f, 0.f);
      xB = xpB ? *(const float4*)(xpB + off) : make_float4(0.f, 0.f, 0.f, 0.f);
      wA = *(const float4*)(wpA + off);
      wB = *(const float4*)(wpB + off);
      if (lwp) {
        lw4 = *(const float4*)(lwp + off);
        lb4 = *(const float4*)(lbp + off);
      }
    }
    const int cur = i & 1;
#pragma unroll
    for (int kk = 0; kk < 32; ++kk) {
      float4 xv = *(const float4*)&Xl[cur][kk][mi * 4];
      float4 wv = *(const float4*)&Wl[cur][kk][ni * 4];
      float xa[4] = {xv.x, xv.y, xv.z, xv.w};
      float wa[4] = {wv.x, wv.y, wv.z, wv.w};
#pragma unroll
      for (int a2 = 0; a2 < 4; ++a2)
#pragma unroll
        for (int c2 = 0; c2 < 4; ++c2)
          acc[a2][c2] = fmaf(xa[a2], wa[c2], acc[a2][c2]);
    }
    if (i + 1 < K32) {
      if (xstats) {
        xA.x = (xA.x - mnA) * rsA * lw4.x + lb4.x;
        xA.y = (xA.y - mnA) * rsA * lw4.y + lb4.y;
        xA.z = (xA.z - mnA) * rsA * lw4.z + lb4.z;
        xA.w = (xA.w - mnA) * rsA * lw4.w + lb4.w;
        xB.x = (xB.x - mnB) * rsB * lw4.x + lb4.x;
        xB.y = (xB.y - mnB) * rsB * lw4.y + lb4.y;
        xB.z = (xB.z - mnB) * rsB * lw4.z + lb4.z;
        xB.w = (xB.w - mnB) * rsB * lw4.w + lb4.w;
      }
      __syncthreads();
      const int nxt = cur ^ 1;
      Xl[nxt][lc + 0][lr] = xA.x; Xl[nxt][lc + 1][lr] = xA.y;
      Xl[nxt][lc + 2][lr] = xA.z; Xl[nxt][lc + 3][lr] = xA.w;
      Xl[nxt][lc + 0][lr + 32] = xB.x; Xl[nxt][lc + 1][lr + 32] = xB.y;
      Xl[nxt][lc + 2][lr + 32] = xB.z; Xl[nxt][lc + 3][lr + 32] = xB.w;
      Wl[nxt][lc + 0][lr] = wA.x; Wl[nxt][lc + 1][lr] = wA.y;
      Wl[nxt][lc + 2][lr] = wA.z; Wl[nxt][lc + 3][lr] = wA.w;
      Wl[nxt][lc + 0][lr + 32] = wB.x; Wl[nxt][lc + 1][lr + 32] = wB.y;
      Wl[nxt][lc + 2][lr + 32] = wB.z; Wl[nxt][lc + 3][lr + 32] = wB.w;
      __syncthreads();
    }
  }

  const int n = n0 + ni * 4;
  // ---- write this split's partial via coherent (L2-bypassing) stores ----
  {
    float* base = Pp + (long long)blockIdx.z * M * N;
#pragma unroll
    for (int i = 0; i < 4; ++i) {
      int m = m0 + mi * 4 + i;
      if (m >= M) continue;
      float* row = base + (long long)m * N + n;
      agent_store(row + 0, acc[i][0]);
      agent_store(row + 1, acc[i][1]);
      agent_store(row + 2, acc[i][2]);
      agent_store(row + 3, acc[i][3]);
    }
  }
  asm volatile("s_waitcnt vmcnt(0)" ::: "memory");  // my stores retired
  __syncthreads();                                  // all threads' stores done
  if (tid == 0)
    sflag = (__hip_atomic_fetch_add(tilecnt + blockIdx.y * gridDim.x +
                                        blockIdx.x,
                                    1, __ATOMIC_RELAXED,
                                    __HIP_MEMORY_SCOPE_AGENT) == splits - 1);
  __syncthreads();
  if (!sflag) return;  // uniform

  // ---- last block: reduce partials (fixed order) + epilogue ----
  float4 bv = *(const float4*)(bias + n);
#pragma unroll
  for (int i = 0; i < 4; ++i) {
    int m = m0 + mi * 4 + i;
    if (m >= M) continue;
    float4 v = make_float4(0.f, 0.f, 0.f, 0.f);
    for (int sp = 0; sp < splits; ++sp) {
      const float* p = Pp + (long long)sp * M * N + (long long)m * N + n;
      v.x += agent_load(p + 0);
      v.y += agent_load(p + 1);
      v.z += agent_load(p + 2);
      v.w += agent_load(p + 3);
    }
    v.x += bv.x; v.y += bv.y; v.z += bv.z; v.w += bv.w;
    int b = m / St, s = m - b * St;
    if (resY) {
      float4 rv =
          *(const float4*)(resY + (long long)b * rbs + (long long)s * ldr + n);
      if (rstats) {
        float rm = rstats[2 * m], rr = rstats[2 * m + 1];
        float4 rw = *(const float4*)(rlnw + n);
        float4 rb2 = *(const float4*)(rlnb + n);
        rv.x = (rv.x - rm) * rr * rw.x + rb2.x;
        rv.y = (rv.y - rm) * rr * rw.y + rb2.y;
        rv.z = (rv.z - rm) * rr * rw.z + rb2.z;
        rv.w = (rv.w - rm) * rr * rw.w + rb2.w;
      }
      v.x += rv.x; v.y += rv.y; v.z += rv.z; v.w += rv.w;
    }
    if (relu) {
      v.x = fmaxf(v.x, 0.f); v.y = fmaxf(v.y, 0.f);
      v.z = fmaxf(v.z, 0.f); v.w = fmaxf(v.w, 0.f);
    }
    float* op = out + (long long)b * obs + (long long)s * ldo + n;
    if (ostats) {  // row-stats pass will re-read -> must be coherent
      agent_store(op + 0, v.x);
      agent_store(op + 1, v.y);
      agent_store(op + 2, v.z);
      agent_store(op + 3, v.w);
    } else {
      *(float4*)op = v;
    }
  }

  // ---- last tile in row-group computes LN stats of out rows ----
  if (ostats) {
    asm volatile("s_waitcnt vmcnt(0)" ::: "memory");
    __syncthreads();
    if (tid == 0)
      sflag = (__hip_atomic_fetch_add(rowcnt + blockIdx.x, 1,
                                      __ATOMIC_RELAXED,
                                      __HIP_MEMORY_SCOPE_AGENT) == Nt - 1);
    __syncthreads();
    if (!sflag) return;  // uniform
    for (int r = wid; r < 64; r += 4) {
      int m = m0 + r;
      if (m >= M) continue;
      int b = m / St, s = m - b * St;
      const float* row = out + (long long)b * obs + (long long)s * ldo;
      float x[16];
#pragma unroll
      for (int it = 0; it < 4; ++it) {
        const float* p = row + it * 256 + lane * 4;
        x[it * 4 + 0] = agent_load(p + 0);
        x[it * 4 + 1] = agent_load(p + 1);
        x[it * 4 + 2] = agent_load(p + 2);
        x[it * 4 + 3] = agent_load(p + 3);
      }
      float sm = 0.f;
#pragma unroll
      for (int j = 0; j < 16; ++j) sm += x[j];
      sm = wave_sum(sm) * (1.f / 1024.f);
      float s2 = 0.f;
#pragma unroll
      for (int j = 0; j < 16; ++j) {
        float d = x[j] - sm;
        s2 += d * d;
      }
      s2 = wave_sum(s2) * (1.f / 1024.f);
      if (lane == 0) {
        ostats[2 * m] = sm;
        ostats[2 * m + 1] = rsqrtf(s2 + 1e-5f);
      }
    }
  }
}

// ------- attention: 4 waves per block, one wave per (b, h, sq) job ---------
__global__ __launch_bounds__(256) void attn_kernel(
    const float* __restrict__ Qp, int q_rs, long long q_bs,
    const float* __restrict__ Kp, int k_rs, long long k_bs,
    const float* __restrict__ Vp, int v_rs, long long v_bs,
    float* __restrict__ Op, int o_rs, long long o_bs,
    int Sq, int Skv) {
  const int lane = threadIdx.x & 63, wid = threadIdx.x >> 6;
  __shared__ float sc[4][72];
  const int njobs = 2 * 8 * Sq;
  for (int base = blockIdx.x * 4; base < njobs; base += gridDim.x * 4) {
    int job = base + wid;
    if (job >= njobs) return;  // wave-independent; no barriers used
    int b = job / (8 * Sq);
    int rr = job - b * 8 * Sq;
    int h = rr / Sq;
    int sq = rr - h * Sq;
    const float* qrow =
        Qp + (long long)b * q_bs + (long long)sq * q_rs + h * 128;
    float q0 = qrow[lane], q1 = qrow[lane + 64];
    const float* kb = Kp + (long long)b * k_bs + h * 128;
    for (int sk = 0; sk < Skv; ++sk) {
      const float* kr = kb + (long long)sk * k_rs;
      float p = fmaf(q0, kr[lane], q1 * kr[lane + 64]);
      p = wave_sum(p);
      if (lane == 0) sc[wid][sk] = p * 0.08838834764831845f;  // 1/sqrt(128)
    }
    float m = -3.4e38f;
    for (int i = lane; i < Skv; i += 64) m = fmaxf(m, sc[wid][i]);
    m = wave_max(m);
    float ssum = 0.f;
    for (int i = lane; i < Skv; i += 64) {
      float e = expf(sc[wid][i] - m);
      sc[wid][i] = e;
      ssum += e;
    }
    ssum = wave_sum(ssum);
    float o0 = 0.f, o1 = 0.f;
    const float* vb = Vp + (long long)b * v_bs + h * 128;
    for (int sk = 0; sk < Skv; ++sk) {
      float w = sc[wid][sk];
      const float* vr = vb + (long long)sk * v_rs;
      o0 = fmaf(w, vr[lane], o0);
      o1 = fmaf(w, vr[lane + 64], o1);
    }
    float inv = 1.f / ssum;
    float* orow = Op + (long long)b * o_bs + (long long)sq * o_rs + h * 128;
    orow[lane] = o0 * inv;
    orow[lane + 64] = o1 * inv;
  }
}

// ---------------- small preprocessing kernels ----------------
__global__ __launch_bounds__(256) void copy_cur_kernel(
    const float* __restrict__ emb, float* __restrict__ cur) {
  int idx = blockIdx.x * 256 + threadIdx.x;
  int b = idx >> 16;
  int r = idx & 65535;
  cur[(long long)b * 73728 + r] = emb[idx];
}

__global__ __launch_bounds__(256) void xmean_kernel(
    const float* __restrict__ emb, float* __restrict__ xmean) {
  int idx = blockIdx.x * 256 + threadIdx.x;
  int b = idx >> 10, d = idx & 1023;
  float s = 0.f;
  for (int ss = 0; ss < 64; ++ss) s += emb[b * 65536 + ss * 1024 + d];
  xmean[idx] = s * (1.f / 64.f);
}

__global__ __launch_bounds__(256) void temp_kernel(
    const float* __restrict__ emb, const float* __restrict__ tw,
    const float* __restrict__ tb, float* __restrict__ tempv) {
  __shared__ float red[4];
  int b = blockIdx.x;
  int wid = threadIdx.x >> 6, lane = threadIdx.x & 63;
  float acc = 0.f;
  for (int s = wid; s < 64; s += 4) {
    const float* x = emb + b * 65536 + s * 1024;
    float p = 0.f;
#pragma unroll
    for (int it = 0; it < 4; ++it) {
      float4 xv = *(const float4*)(x + it * 256 + lane * 4);
      float4 wv = *(const float4*)(tw + it * 256 + lane * 4);
      p += xv.x * wv.x + xv.y * wv.y + xv.z * wv.z + xv.w * wv.w;
    }
    p = wave_sum(p);
    acc += 1.f / (1.f + expf(-(p + tb[0])));
  }
  if (lane == 0) red[wid] = acc;
  __syncthreads();
  if (threadIdx.x == 0)
    tempv[b] = (red[0] + red[1] + red[2] + red[3]) * (1.f / 64.f);
}

__global__ __launch_bounds__(256) void style_kernel(
    const float* __restrict__ xmean, const float* __restrict__ sw,
    const float* __restrict__ sb, float* __restrict__ stylev) {
  int wid = threadIdx.x >> 6, lane = threadIdx.x & 63;
  int d = blockIdx.x * 4 + wid;
  const float* wr = sw + (long long)d * 1024;
  float a0 = 0.f, a1 = 0.f;
#pragma unroll
  for (int it = 0; it < 4; ++it) {
    float4 wv = *(const float4*)(wr + it * 256 + lane * 4);
    float4 x0 = *(const float4*)(xmean + it * 256 + lane * 4);
    float4 x1 = *(const float4*)(xmean + 1024 + it * 256 + lane * 4);
    a0 += wv.x * x0.x + wv.y * x0.y + wv.z * x0.z + wv.w * x0.w;
    a1 += wv.x * x1.x + wv.y * x1.y + wv.z * x1.z + wv.w * x1.w;
  }
  a0 = wave_sum(a0);
  a1 = wave_sum(a1);
  if (lane == 0) {
    stylev[d] = a0 + sb[d];
    stylev[1024 + d] = a1 + sb[d];
  }
}

// -------- logits: z = LN(Y[:,St-1]) + style, one wave per vocab row --------
__global__ __launch_bounds__(256) void logits_kernel(
    const float* __restrict__ Y, const float* __restrict__ ystats,
    const float* __restrict__ lnw, const float* __restrict__ lnb, int St,
    const float* __restrict__ stylev, const float* __restrict__ Wo,
    const float* __restrict__ bo, const float* __restrict__ tempv,
    float* __restrict__ outl, int t) {
  int wid = threadIdx.x >> 6, lane = threadIdx.x & 63;
  int n = blockIdx.x * 4 + wid;
  const float* wr = Wo + (long long)n * 1024;
  int m0 = St - 1, m1 = St + St - 1;
  const float* y0 = Y + (long long)(St - 1) * 1024;
  const float* y1 = Y + 73728 + (long long)(St - 1) * 1024;
  float mean0 = ystats[2 * m0], rstd0 = ystats[2 * m0 + 1];
  float mean1 = ystats[2 * m1], rstd1 = ystats[2 * m1 + 1];
  float a0 = 0.f, a1 = 0.f;
#pragma unroll
  for (int it = 0; it < 4; ++it) {
    int off = it * 256 + lane * 4;
    float4 wv = *(const float4*)(wr + off);
    float4 lw = *(const float4*)(lnw + off);
    float4 lb = *(const float4*)(lnb + off);
    float4 s0 = *(const float4*)(stylev + off);
    float4 s1 = *(const float4*)(stylev + 1024 + off);
    float4 x0 = *(const float4*)(y0 + off);
    float4 x1 = *(const float4*)(y1 + off);
    float z0x = (x0.x - mean0) * rstd0 * lw.x + lb.x + s0.x;
    float z0y = (x0.y - mean0) * rstd0 * lw.y + lb.y + s0.y;
    float z0z = (x0.z - mean0) * rstd0 * lw.z + lb.z + s0.z;
    float z0w = (x0.w - mean0) * rstd0 * lw.w + lb.w + s0.w;
    float z1x = (x1.x - mean1) * rstd1 * lw.x + lb.x + s1.x;
    float z1y = (x1.y - mean1) * rstd1 * lw.y + lb.y + s1.y;
    float z1z = (x1.z - mean1) * rstd1 * lw.z + lb.z + s1.z;
    float z1w = (x1.w - mean1) * rstd1 * lw.w + lb.w + s1.w;
    a0 += wv.x * z0x + wv.y * z0y + wv.z * z0z + wv.w * z0w;
    a1 += wv.x * z1x + wv.y * z1y + wv.z * z1z + wv.w * z1w;
  }
  a0 = wave_sum(a0);
  a1 = wave_sum(a1);
  if (lane == 0) {
    float bb = bo[n];
    outl[(long long)(0 * 8 + t) * 32000 + n] = (a0 + bb) / tempv[0];
    outl[(long long)(1 * 8 + t) * 32000 + n] = (a1 + bb) / tempv[1];
  }
}

// -------- Gumbel argmax sampling (exact partitionable threefry) + append ----
__global__ __launch_bounds__(1024) void sample_kernel(
    const float* __restrict__ logits, const float* __restrict__ Wo,
    float* __restrict__ tok_f, float* __restrict__ cur, int St,
    uint32_t fk0, uint32_t fk1, int t) {
  int b = blockIdx.x;
  const float* lg = logits + (long long)(b * 8 + t) * 32000;
  float best = -3.4e38f;
  int bi = 0x7fffffff;
  for (int n = threadIdx.x; n < 32000; n += 1024) {
    uint32_t r0, r1;
    threefry2x32(fk0, fk1, 0u, (uint32_t)(b * 32000 + n), &r0, &r1);
    uint32_t bits = (r0 ^ r1) >> 9;
    float u = __uint_as_float(0x3f800000u | bits) - 1.0f;
    if (u < 1.1754944e-38f) u = 1.1754944e-38f;
    float g = -logf(-logf(u));
    float val = lg[n] + g;
    if (val > best) { best = val; bi = n; }
  }
  __shared__ float bv[1024];
  __shared__ int bix[1024];
  bv[threadIdx.x] = best;
  bix[threadIdx.x] = bi;
  __syncthreads();
  for (int s = 512; s > 0; s >>= 1) {
    if (threadIdx.x < s) {
      float ov = bv[threadIdx.x + s];
      int oi = bix[threadIdx.x + s];
      if (ov > bv[threadIdx.x] ||
          (ov == bv[threadIdx.x] && oi < bix[threadIdx.x])) {
        bv[threadIdx.x] = ov;
        bix[threadIdx.x] = oi;
      }
    }
    __syncthreads();
  }
  int tok = bix[0];
  if (threadIdx.x == 0) tok_f[b * 8 + t] = (float)tok;
  cur[(long long)b * 73728 + (long long)St * 1024 + threadIdx.x] =
      Wo[(long long)tok * 1024 + threadIdx.x];
}

// ============================================================================
extern "C" void kernel_launch(void* const* d_in, const int* in_sizes, int n_in,
                              void* d_out, int out_size, void* d_ws,
                              size_t ws_size, hipStream_t stream) {
  const float* emb = (const float*)d_in[0];
  const float* sa_in_w = (const float*)d_in[1];
  const float* sa_in_b = (const float*)d_in[2];
  const float* sa_out_w = (const float*)d_in[3];
  const float* sa_out_b = (const float*)d_in[4];
  const float* ca_in_w = (const float*)d_in[5];
  const float* ca_in_b = (const float*)d_in[6];
  const float* ca_out_w = (const float*)d_in[7];
  const float* ca_out_b = (const float*)d_in[8];
  const float* ff1_w = (const float*)d_in[9];
  const float* ff1_b = (const float*)d_in[10];
  const float* ff2_w = (const float*)d_in[11];
  const float* ff2_b = (const float*)d_in[12];
  const float* ln_w = (const float*)d_in[13];
  const float* ln_b = (const float*)d_in[14];
  const float* out_w = (const float*)d_in[15];
  const float* out_b = (const float*)d_in[16];
  const float* temp_w = (const float*)d_in[17];
  const float* temp_b = (const float*)d_in[18];
  const float* style_w = (const float*)d_in[21];
  const float* style_b = (const float*)d_in[22];

  float* ws = (float*)d_ws;
  float* cur = ws;                          // [2][72][1024]
  float* Qb = cur + 147456;                 // [2][72][3072]
  float* Tb = Qb + 442368;                  // [2][72][1024]
  float* T2 = Tb + 147456;                  // [2][72][1024]
  float* Fb = T2 + 147456;                  // [2][72][4096]
  float* Yb = Fb + 589824;                  // 6 x [2][72][1024]
  float* cakv = Yb + 884736;                // [2][2][64][2048]
  float* Pp = cakv + 524288;                // split-K partials (2.4M floats)
  float* xmean = Pp + 2400000;              // 2048
  float* stylev = xmean + 2048;             // 2048
  float* tempv = stylev + 2048;             // 16
  float* statsb = tempv + 16;               // 6 x 288
  int* cntpool = (int*)(statsb + 1728);     // 100 x 256 ints

  float* toks_out = (float*)d_out;
  float* logits_out = toks_out + 16;

  auto Y = [&](int l, int j) { return Yb + (size_t)(l * 3 + j) * 147456; };
  auto SS = [&](int l, int j) { return statsb + (size_t)(l * 3 + j) * 288; };

  // zero the atomic-counter pool (graph node, runs each replay)
  hipMemsetAsync(cntpool, 0, 100 * 256 * sizeof(int), stream);

  int inst = 0;
  auto g3 = [&](const float* X, long long xbs, int ldx, const float* xst,
                const float* xlw, const float* xlb, const float* W, int ldw,
                const float* bias, const float* resY, long long rbs, int ldr,
                const float* rst, const float* rlw, const float* rlb,
                float* out, long long obs, int ldo, float* ost, int St, int M,
                int N, int K, int splits, int relu) {
    dim3 grid((unsigned)((M + 63) / 64), (unsigned)(N / 64),
              (unsigned)splits);
    int* tc = cntpool + inst * 256;
    ++inst;
    gemm3_kernel<<<grid, 256, 0, stream>>>(
        X, xbs, ldx, xst, xlw, xlb, W, ldw, bias, resY, rbs, ldr, rst, rlw,
        rlb, Pp, out, obs, ldo, ost, St, M, N, K / (32 * splits), relu, tc,
        tc + 200);
  };

  // ---- precompute ----
  copy_cur_kernel<<<512, 256, 0, stream>>>(emb, cur);
  xmean_kernel<<<8, 256, 0, stream>>>(emb, xmean);
  temp_kernel<<<2, 256, 0, stream>>>(emb, temp_w, temp_b, tempv);
  style_kernel<<<256, 256, 0, stream>>>(xmean, style_w, style_b, stylev);
  for (int l = 0; l < 2; ++l)  // cross-attn K,V from constant memory input
    g3(emb, 64 * 1024, 1024, nullptr, nullptr, nullptr,
       ca_in_w + (size_t)(l * 3072 + 1024) * 1024, 1024,
       ca_in_b + l * 3072 + 1024, nullptr, 0, 0, nullptr, nullptr, nullptr,
       cakv + (size_t)l * 2 * 64 * 2048, 64 * 2048, 2048, nullptr, 64, 128,
       2048, 1024, 4, 0);

  for (int t = 0; t < 8; ++t) {
    const int St = 64 + t;
    const int M = 2 * St;
    const int ablk = (2 * 8 * St + 3) / 4;
    for (int l = 0; l < 2; ++l) {
      const float* X0 = (l == 0) ? cur : Y(0, 2);
      const float* X0st = (l == 0) ? nullptr : SS(0, 2);
      const float* X0lw = (l == 0) ? nullptr : ln_w + (0 * 3 + 2) * 1024;
      const float* X0lb = (l == 0) ? nullptr : ln_b + (0 * 3 + 2) * 1024;

      // 1) self-attn QKV (fused bias) -> Qb
      g3(X0, 72 * 1024, 1024, X0st, X0lw, X0lb,
         sa_in_w + (size_t)l * 3072 * 1024, 1024, sa_in_b + l * 3072, nullptr,
         0, 0, nullptr, nullptr, nullptr, Qb, 72 * 3072, 3072, nullptr, St, M,
         3072, 1024, 4, 0);
      // 2) self-attention
      attn_kernel<<<ablk, 256, 0, stream>>>(
          Qb, 3072, 72 * 3072, Qb + 1024, 3072, 72 * 3072, Qb + 2048, 3072,
          72 * 3072, Tb, 1024, 72 * 1024, St, St);
      // 3) out-proj + bias + residual(X0,LN) -> Y0 raw, stats0
      g3(Tb, 72 * 1024, 1024, nullptr, nullptr, nullptr,
         sa_out_w + (size_t)l * 1024 * 1024, 1024, sa_out_b + l * 1024, X0,
         72 * 1024, 1024, X0st, X0lw, X0lb, Y(l, 0), 72 * 1024, 1024,
         SS(l, 0), St, M, 1024, 1024, 8, 0);
      // 4) cross-attn Q = LN(Y0) @ Wq + bq -> T2
      g3(Y(l, 0), 72 * 1024, 1024, SS(l, 0), ln_w + (l * 3 + 0) * 1024,
         ln_b + (l * 3 + 0) * 1024, ca_in_w + (size_t)l * 3072 * 1024, 1024,
         ca_in_b + l * 3072, nullptr, 0, 0, nullptr, nullptr, nullptr, T2,
         72 * 1024, 1024, nullptr, St, M, 1024, 1024, 8, 0);
      // 5) cross-attention
      attn_kernel<<<ablk, 256, 0, stream>>>(
          T2, 1024, 72 * 1024, cakv + (size_t)l * 2 * 64 * 2048, 2048,
          64 * 2048, cakv + (size_t)l * 2 * 64 * 2048 + 1024, 2048, 64 * 2048,
          Tb, 1024, 72 * 1024, St, 64);
      // 6) ca out-proj + bias + residual(LN(Y0)) -> Y1 raw, stats1
      g3(Tb, 72 * 1024, 1024, nullptr, nullptr, nullptr,
         ca_out_w + (size_t)l * 1024 * 1024, 1024, ca_out_b + l * 1024,
         Y(l, 0), 72 * 1024, 1024, SS(l, 0), ln_w + (l * 3 + 0) * 1024,
         ln_b + (l * 3 + 0) * 1024, Y(l, 1), 72 * 1024, 1024, SS(l, 1), St, M,
         1024, 1024, 8, 0);
      // 7) FFN1: relu(LN(Y1) @ W1 + b1) -> Fb
      g3(Y(l, 1), 72 * 1024, 1024, SS(l, 1), ln_w + (l * 3 + 1) * 1024,
         ln_b + (l * 3 + 1) * 1024, ff1_w + (size_t)l * 4096 * 1024, 1024,
         ff1_b + l * 4096, nullptr, 0, 0, nullptr, nullptr, nullptr, Fb,
         72 * 4096, 4096, nullptr, St, M, 4096, 1024, 4, 1);
      // 8) FFN2: Fb @ W2 + b2 + residual(LN(Y1)) -> Y2 raw, stats2
      g3(Fb, 72 * 4096, 4096, nullptr, nullptr, nullptr,
         ff2_w + (size_t)l * 1024 * 4096, 4096, ff2_b + l * 1024, Y(l, 1),
         72 * 1024, 1024, SS(l, 1), ln_w + (l * 3 + 1) * 1024,
         ln_b + (l * 3 + 1) * 1024, Y(l, 2), 72 * 1024, 1024, SS(l, 2), St, M,
         1024, 4096, 16, 0);
    }
    // logits from LN(Y2 of layer 1) + style
    logits_kernel<<<8000, 256, 0, stream>>>(
        Y(1, 2), SS(1, 2), ln_w + (1 * 3 + 2) * 1024,
        ln_b + (1 * 3 + 2) * 1024, St, stylev, out_w, out_b, tempv,
        logits_out, t);
    uint32_t fk0, fk1;
    threefry2x32(0u, 42u, 0u, (uint32_t)t, &fk0, &fk1);
    sample_kernel<<<2, 1024, 0, stream>>>(logits_out, out_w, toks_out, cur,
                                          St, fk0, fk1, t);
  }
}

// Round 13
// 6346.575 us; speedup vs baseline: 3.5829x; 1.1496x over previous
//
#include <hip/hip_runtime.h>
#include <stdint.h>

// ---------------- threefry2x32 (exact JAX schedule) ----------------
__host__ __device__ inline void threefry2x32(uint32_t k0, uint32_t k1,
                                             uint32_t x0, uint32_t x1,
                                             uint32_t* o0, uint32_t* o1) {
  uint32_t ks2 = 0x1BD11BDAu ^ k0 ^ k1;
  x0 += k0; x1 += k1;
#define TF_R(x, r) (((x) << (r)) | ((x) >> (32 - (r))))
#define TF_ROUND(r) { x0 += x1; x1 = TF_R(x1, r); x1 ^= x0; }
  TF_ROUND(13) TF_ROUND(15) TF_ROUND(26) TF_ROUND(6)
  x0 += k1; x1 += ks2 + 1u;
  TF_ROUND(17) TF_ROUND(29) TF_ROUND(16) TF_ROUND(24)
  x0 += ks2; x1 += k0 + 2u;
  TF_ROUND(13) TF_ROUND(15) TF_ROUND(26) TF_ROUND(6)
  x0 += k0; x1 += k1 + 3u;
  TF_ROUND(17) TF_ROUND(29) TF_ROUND(16) TF_ROUND(24)
  x0 += k1; x1 += ks2 + 4u;
  TF_ROUND(13) TF_ROUND(15) TF_ROUND(26) TF_ROUND(6)
  x0 += ks2; x1 += k0 + 5u;
  *o0 = x0; *o1 = x1;
#undef TF_ROUND
#undef TF_R
}

__device__ __forceinline__ float wave_sum(float v) {
#pragma unroll
  for (int o = 32; o > 0; o >>= 1) v += __shfl_xor(v, o, 64);
  return v;
}
__device__ __forceinline__ float wave_max(float v) {
#pragma unroll
  for (int o = 32; o > 0; o >>= 1) v = fmaxf(v, __shfl_xor(v, o, 64));
  return v;
}

__device__ __forceinline__ void agent_store(float* p, float v) {
  __hip_atomic_store(p, v, __ATOMIC_RELAXED, __HIP_MEMORY_SCOPE_AGENT);
}
__device__ __forceinline__ float agent_load(const float* p) {
  return __hip_atomic_load(p, __ATOMIC_RELAXED, __HIP_MEMORY_SCOPE_AGENT);
}

union PackF2 {
  float2 f;
  unsigned long long u;
};

// ============================================================================
// gemm3: split-K GEMM, fence-free fused reduction epilogue.
//  - Partial tiles stored in a LANE-CONTIGUOUS swizzled layout:
//    element (tile-local row mrow, col ni*4+q) at offset (mrow*4+q)*16+ni.
//    Every scalar agent store/load is then coalesced (64B packed txns).
//  - vmcnt(0)+barrier, relaxed agent atomicAdd elects the LAST block per
//    tile; it reduces splits in fixed order, adds bias/residual(+LN)/relu,
//    writes `out` with NORMAL stores (consumed by later kernels only).
//  - LN stats: elected tile block reduces per-row (sum, sumsq) over its 64
//    cols via a fixed 16-lane shuffle tree, publishes one packed 8B coherent
//    word per row; last tile per row-group (rowcnt) combines Nt tile sums
//    (fixed tree) -> ostats.  Deterministic throughout.
// X rows batch-mapped m -> (b=m/St, s=m%St). Optional on-the-fly X-side LN.
// ============================================================================
__global__ __launch_bounds__(256) void gemm3_kernel(
    const float* __restrict__ X, long long xbs, int ldx,
    const float* __restrict__ xstats, const float* __restrict__ xlnw,
    const float* __restrict__ xlnb,
    const float* __restrict__ W, int ldw, const float* __restrict__ bias,
    const float* __restrict__ resY, long long rbs, int ldr,
    const float* __restrict__ rstats, const float* __restrict__ rlnw,
    const float* __restrict__ rlnb,
    float* __restrict__ Pp, unsigned long long* __restrict__ Srow,
    float* __restrict__ out, long long obs, int ldo,
    float* __restrict__ ostats,
    int St, int M, int N, int K32, int relu,
    int* __restrict__ tilecnt, int* __restrict__ rowcnt) {
  __shared__ __align__(16) float Xl[2][32][68];
  __shared__ __align__(16) float Wl[2][32][68];
  __shared__ int sflag;
  const int tid = threadIdx.x;
  const int m0 = blockIdx.x * 64;
  const int n0 = blockIdx.y * 64;
  const int splits = gridDim.z;
  const int Nt = gridDim.y;
  const int tile = blockIdx.y * gridDim.x + blockIdx.x;
  const int nTiles = gridDim.x * gridDim.y;
  const long long kbase = (long long)blockIdx.z * K32 * 32;
  const int mi = tid >> 4, ni = tid & 15, lr = tid >> 3, lc = (tid & 7) * 4;
  const int wid = tid >> 6, lane = tid & 63;

  const int mA = m0 + lr, mB = m0 + lr + 32;
  const float* xpA = nullptr;
  const float* xpB = nullptr;
  float mnA = 0.f, rsA = 1.f, mnB = 0.f, rsB = 1.f;
  if (mA < M) {
    int b = mA / St, s = mA - b * St;
    xpA = X + (long long)b * xbs + (long long)s * ldx + kbase + lc;
    if (xstats) { mnA = xstats[2 * mA]; rsA = xstats[2 * mA + 1]; }
  }
  if (mB < M) {
    int b = mB / St, s = mB - b * St;
    xpB = X + (long long)b * xbs + (long long)s * ldx + kbase + lc;
    if (xstats) { mnB = xstats[2 * mB]; rsB = xstats[2 * mB + 1]; }
  }
  const float* wpA = W + (long long)(n0 + lr) * ldw + kbase + lc;
  const float* wpB = W + (long long)(n0 + lr + 32) * ldw + kbase + lc;
  const float* lwp = xlnw ? xlnw + kbase + lc : nullptr;
  const float* lbp = xlnb ? xlnb + kbase + lc : nullptr;

  float4 xA = xpA ? *(const float4*)xpA : make_float4(0.f, 0.f, 0.f, 0.f);
  float4 xB = xpB ? *(const float4*)xpB : make_float4(0.f, 0.f, 0.f, 0.f);
  float4 wA = *(const float4*)wpA;
  float4 wB = *(const float4*)wpB;
  float4 lw4 = make_float4(1.f, 1.f, 1.f, 1.f);
  float4 lb4 = make_float4(0.f, 0.f, 0.f, 0.f);
  if (lwp) { lw4 = *(const float4*)lwp; lb4 = *(const float4*)lbp; }

  float acc[4][4];
#pragma unroll
  for (int i = 0; i < 4; ++i)
#pragma unroll
    for (int j = 0; j < 4; ++j) acc[i][j] = 0.f;

  if (xstats) {
    xA.x = (xA.x - mnA) * rsA * lw4.x + lb4.x;
    xA.y = (xA.y - mnA) * rsA * lw4.y + lb4.y;
    xA.z = (xA.z - mnA) * rsA * lw4.z + lb4.z;
    xA.w = (xA.w - mnA) * rsA * lw4.w + lb4.w;
    xB.x = (xB.x - mnB) * rsB * lw4.x + lb4.x;
    xB.y = (xB.y - mnB) * rsB * lw4.y + lb4.y;
    xB.z = (xB.z - mnB) * rsB * lw4.z + lb4.z;
    xB.w = (xB.w - mnB) * rsB * lw4.w + lb4.w;
  }

  Xl[0][lc + 0][lr] = xA.x; Xl[0][lc + 1][lr] = xA.y;
  Xl[0][lc + 2][lr] = xA.z; Xl[0][lc + 3][lr] = xA.w;
  Xl[0][lc + 0][lr + 32] = xB.x; Xl[0][lc + 1][lr + 32] = xB.y;
  Xl[0][lc + 2][lr + 32] = xB.z; Xl[0][lc + 3][lr + 32] = xB.w;
  Wl[0][lc + 0][lr] = wA.x; Wl[0][lc + 1][lr] = wA.y;
  Wl[0][lc + 2][lr] = wA.z; Wl[0][lc + 3][lr] = wA.w;
  Wl[0][lc + 0][lr + 32] = wB.x; Wl[0][lc + 1][lr + 32] = wB.y;
  Wl[0][lc + 2][lr + 32] = wB.z; Wl[0][lc + 3][lr + 32] = wB.w;
  __syncthreads();

  for (int i = 0; i < K32; ++i) {
    if (i + 1 < K32) {
      int off = (i + 1) * 32;
      xA = xpA ? *(const float4*)(xpA + off) : make_float4(0.f, 0.f, 0.f, 0.f);
      xB = xpB ? *(const float4*)(xpB + off) : make_float4(0.f, 0.f, 0.f, 0.f);
      wA = *(const float4*)(wpA + off);
      wB = *(const float4*)(wpB + off);
      if (lwp) {
        lw4 = *(const float4*)(lwp + off);
        lb4 = *(const float4*)(lbp + off);
      }
    }
    const int cur = i & 1;
#pragma unroll
    for (int kk = 0; kk < 32; ++kk) {
      float4 xv = *(const float4*)&Xl[cur][kk][mi * 4];
      float4 wv = *(const float4*)&Wl[cur][kk][ni * 4];
      float xa[4] = {xv.x, xv.y, xv.z, xv.w};
      float wa[4] = {wv.x, wv.y, wv.z, wv.w};
#pragma unroll
      for (int a2 = 0; a2 < 4; ++a2)
#pragma unroll
        for (int c2 = 0; c2 < 4; ++c2)
          acc[a2][c2] = fmaf(xa[a2], wa[c2], acc[a2][c2]);
    }
    if (i + 1 < K32) {
      if (xstats) {
        xA.x = (xA.x - mnA) * rsA * lw4.x + lb4.x;
        xA.y = (xA.y - mnA) * rsA * lw4.y + lb4.y;
        xA.z = (xA.z - mnA) * rsA * lw4.z + lb4.z;
        xA.w = (xA.w - mnA) * rsA * lw4.w + lb4.w;
        xB.x = (xB.x - mnB) * rsB * lw4.x + lb4.x;
        xB.y = (xB.y - mnB) * rsB * lw4.y + lb4.y;
        xB.z = (xB.z - mnB) * rsB * lw4.z + lb4.z;
        xB.w = (xB.w - mnB) * rsB * lw4.w + lb4.w;
      }
      __syncthreads();
      const int nxt = cur ^ 1;
      Xl[nxt][lc + 0][lr] = xA.x; Xl[nxt][lc + 1][lr] = xA.y;
      Xl[nxt][lc + 2][lr] = xA.z; Xl[nxt][lc + 3][lr] = xA.w;
      Xl[nxt][lc + 0][lr + 32] = xB.x; Xl[nxt][lc + 1][lr + 32] = xB.y;
      Xl[nxt][lc + 2][lr + 32] = xB.z; Xl[nxt][lc + 3][lr + 32] = xB.w;
      Wl[nxt][lc + 0][lr] = wA.x; Wl[nxt][lc + 1][lr] = wA.y;
      Wl[nxt][lc + 2][lr] = wA.z; Wl[nxt][lc + 3][lr] = wA.w;
      Wl[nxt][lc + 0][lr + 32] = wB.x; Wl[nxt][lc + 1][lr + 32] = wB.y;
      Wl[nxt][lc + 2][lr + 32] = wB.z; Wl[nxt][lc + 3][lr + 32] = wB.w;
      __syncthreads();
    }
  }

  // ---- write this split's partial (swizzled lane-contiguous layout) ----
  {
    float* ptile = Pp + ((long long)blockIdx.z * nTiles + tile) * 4096;
#pragma unroll
    for (int i = 0; i < 4; ++i) {
      int mrow = mi * 4 + i;
      if (m0 + mrow >= M) continue;
#pragma unroll
      for (int q = 0; q < 4; ++q)
        agent_store(ptile + (mrow * 4 + q) * 16 + ni, acc[i][q]);
    }
  }
  asm volatile("s_waitcnt vmcnt(0)" ::: "memory");
  __syncthreads();
  if (tid == 0)
    sflag = (__hip_atomic_fetch_add(tilecnt + tile, 1, __ATOMIC_RELAXED,
                                    __HIP_MEMORY_SCOPE_AGENT) == splits - 1);
  __syncthreads();
  if (!sflag) return;  // uniform

  // ---- last block: reduce splits (fixed order) + epilogue ----
  const int n = n0 + ni * 4;
  float4 bv = *(const float4*)(bias + n);
#pragma unroll
  for (int i = 0; i < 4; ++i) {
    int mrow = mi * 4 + i;
    int m = m0 + mrow;
    if (m >= M) continue;
    float4 v = make_float4(0.f, 0.f, 0.f, 0.f);
    for (int sp = 0; sp < splits; ++sp) {
      const float* pt = Pp + ((long long)sp * nTiles + tile) * 4096;
      v.x += agent_load(pt + (mrow * 4 + 0) * 16 + ni);
      v.y += agent_load(pt + (mrow * 4 + 1) * 16 + ni);
      v.z += agent_load(pt + (mrow * 4 + 2) * 16 + ni);
      v.w += agent_load(pt + (mrow * 4 + 3) * 16 + ni);
    }
    v.x += bv.x; v.y += bv.y; v.z += bv.z; v.w += bv.w;
    int b = m / St, s = m - b * St;
    if (resY) {
      float4 rv =
          *(const float4*)(resY + (long long)b * rbs + (long long)s * ldr + n);
      if (rstats) {
        float rm = rstats[2 * m], rr = rstats[2 * m + 1];
        float4 rw = *(const float4*)(rlnw + n);
        float4 rb2 = *(const float4*)(rlnb + n);
        rv.x = (rv.x - rm) * rr * rw.x + rb2.x;
        rv.y = (rv.y - rm) * rr * rw.y + rb2.y;
        rv.z = (rv.z - rm) * rr * rw.z + rb2.z;
        rv.w = (rv.w - rm) * rr * rw.w + rb2.w;
      }
      v.x += rv.x; v.y += rv.y; v.z += rv.z; v.w += rv.w;
    }
    if (relu) {
      v.x = fmaxf(v.x, 0.f); v.y = fmaxf(v.y, 0.f);
      v.z = fmaxf(v.z, 0.f); v.w = fmaxf(v.w, 0.f);
    }
    *(float4*)(out + (long long)b * obs + (long long)s * ldo + n) = v;

    if (ostats) {  // per-row (sum, sumsq) over this tile's 64 cols
      float lsum = v.x + v.y + v.z + v.w;
      float lsq = v.x * v.x + v.y * v.y + v.z * v.z + v.w * v.w;
#pragma unroll
      for (int o = 8; o > 0; o >>= 1) {
        lsum += __shfl_xor(lsum, o, 64);
        lsq += __shfl_xor(lsq, o, 64);
      }
      if (ni == 0) {
        PackF2 pk;
        pk.f = make_float2(lsum, lsq);
        __hip_atomic_store(Srow + (size_t)blockIdx.y * 144 + m, pk.u,
                           __ATOMIC_RELAXED, __HIP_MEMORY_SCOPE_AGENT);
      }
    }
  }

  // ---- last tile in row-group combines Nt tile sums -> ostats ----
  if (ostats) {
    asm volatile("s_waitcnt vmcnt(0)" ::: "memory");
    __syncthreads();
    if (tid == 0)
      sflag = (__hip_atomic_fetch_add(rowcnt + blockIdx.x, 1,
                                      __ATOMIC_RELAXED,
                                      __HIP_MEMORY_SCOPE_AGENT) == Nt - 1);
    __syncthreads();
    if (!sflag) return;  // uniform
    for (int r = wid; r < 64; r += 4) {
      int m = m0 + r;
      if (m >= M) continue;
      float lsum = 0.f, lsq = 0.f;
      if (lane < Nt) {
        PackF2 pk;
        pk.u = __hip_atomic_load(Srow + (size_t)lane * 144 + m,
                                 __ATOMIC_RELAXED, __HIP_MEMORY_SCOPE_AGENT);
        lsum = pk.f.x;
        lsq = pk.f.y;
      }
      lsum = wave_sum(lsum);
      lsq = wave_sum(lsq);
      if (lane == 0) {
        float mean = lsum * (1.f / 1024.f);
        float var = fmaxf(lsq * (1.f / 1024.f) - mean * mean, 0.f);
        ostats[2 * m] = mean;
        ostats[2 * m + 1] = rsqrtf(var + 1e-5f);
      }
    }
  }
}

// ------- attention: 4 waves per block, one wave per (b, h, sq) job ---------
__global__ __launch_bounds__(256) void attn_kernel(
    const float* __restrict__ Qp, int q_rs, long long q_bs,
    const float* __restrict__ Kp, int k_rs, long long k_bs,
    const float* __restrict__ Vp, int v_rs, long long v_bs,
    float* __restrict__ Op, int o_rs, long long o_bs,
    int Sq, int Skv) {
  const int lane = threadIdx.x & 63, wid = threadIdx.x >> 6;
  __shared__ float sc[4][72];
  const int njobs = 2 * 8 * Sq;
  for (int base = blockIdx.x * 4; base < njobs; base += gridDim.x * 4) {
    int job = base + wid;
    if (job >= njobs) return;  // wave-independent; no barriers used
    int b = job / (8 * Sq);
    int rr = job - b * 8 * Sq;
    int h = rr / Sq;
    int sq = rr - h * Sq;
    const float* qrow =
        Qp + (long long)b * q_bs + (long long)sq * q_rs + h * 128;
    float q0 = qrow[lane], q1 = qrow[lane + 64];
    const float* kb = Kp + (long long)b * k_bs + h * 128;
    for (int sk = 0; sk < Skv; ++sk) {
      const float* kr = kb + (long long)sk * k_rs;
      float p = fmaf(q0, kr[lane], q1 * kr[lane + 64]);
      p = wave_sum(p);
      if (lane == 0) sc[wid][sk] = p * 0.08838834764831845f;  // 1/sqrt(128)
    }
    float m = -3.4e38f;
    for (int i = lane; i < Skv; i += 64) m = fmaxf(m, sc[wid][i]);
    m = wave_max(m);
    float ssum = 0.f;
    for (int i = lane; i < Skv; i += 64) {
      float e = expf(sc[wid][i] - m);
      sc[wid][i] = e;
      ssum += e;
    }
    ssum = wave_sum(ssum);
    float o0 = 0.f, o1 = 0.f;
    const float* vb = Vp + (long long)b * v_bs + h * 128;
    for (int sk = 0; sk < Skv; ++sk) {
      float w = sc[wid][sk];
      const float* vr = vb + (long long)sk * v_rs;
      o0 = fmaf(w, vr[lane], o0);
      o1 = fmaf(w, vr[lane + 64], o1);
    }
    float inv = 1.f / ssum;
    float* orow = Op + (long long)b * o_bs + (long long)sq * o_rs + h * 128;
    orow[lane] = o0 * inv;
    orow[lane + 64] = o1 * inv;
  }
}

// ---------------- small preprocessing kernels ----------------
__global__ __launch_bounds__(256) void copy_cur_kernel(
    const float* __restrict__ emb, float* __restrict__ cur) {
  int idx = blockIdx.x * 256 + threadIdx.x;
  int b = idx >> 16;
  int r = idx & 65535;
  cur[(long long)b * 73728 + r] = emb[idx];
}

__global__ __launch_bounds__(256) void xmean_kernel(
    const float* __restrict__ emb, float* __restrict__ xmean) {
  int idx = blockIdx.x * 256 + threadIdx.x;
  int b = idx >> 10, d = idx & 1023;
  float s = 0.f;
  for (int ss = 0; ss < 64; ++ss) s += emb[b * 65536 + ss * 1024 + d];
  xmean[idx] = s * (1.f / 64.f);
}

__global__ __launch_bounds__(256) void temp_kernel(
    const float* __restrict__ emb, const float* __restrict__ tw,
    const float* __restrict__ tb, float* __restrict__ tempv) {
  __shared__ float red[4];
  int b = blockIdx.x;
  int wid = threadIdx.x >> 6, lane = threadIdx.x & 63;
  float acc = 0.f;
  for (int s = wid; s < 64; s += 4) {
    const float* x = emb + b * 65536 + s * 1024;
    float p = 0.f;
#pragma unroll
    for (int it = 0; it < 4; ++it) {
      float4 xv = *(const float4*)(x + it * 256 + lane * 4);
      float4 wv = *(const float4*)(tw + it * 256 + lane * 4);
      p += xv.x * wv.x + xv.y * wv.y + xv.z * wv.z + xv.w * wv.w;
    }
    p = wave_sum(p);
    acc += 1.f / (1.f + expf(-(p + tb[0])));
  }
  if (lane == 0) red[wid] = acc;
  __syncthreads();
  if (threadIdx.x == 0)
    tempv[b] = (red[0] + red[1] + red[2] + red[3]) * (1.f / 64.f);
}

__global__ __launch_bounds__(256) void style_kernel(
    const float* __restrict__ xmean, const float* __restrict__ sw,
    const float* __restrict__ sb, float* __restrict__ stylev) {
  int wid = threadIdx.x >> 6, lane = threadIdx.x & 63;
  int d = blockIdx.x * 4 + wid;
  const float* wr = sw + (long long)d * 1024;
  float a0 = 0.f, a1 = 0.f;
#pragma unroll
  for (int it = 0; it < 4; ++it) {
    float4 wv = *(const float4*)(wr + it * 256 + lane * 4);
    float4 x0 = *(const float4*)(xmean + it * 256 + lane * 4);
    float4 x1 = *(const float4*)(xmean + 1024 + it * 256 + lane * 4);
    a0 += wv.x * x0.x + wv.y * x0.y + wv.z * x0.z + wv.w * x0.w;
    a1 += wv.x * x1.x + wv.y * x1.y + wv.z * x1.z + wv.w * x1.w;
  }
  a0 = wave_sum(a0);
  a1 = wave_sum(a1);
  if (lane == 0) {
    stylev[d] = a0 + sb[d];
    stylev[1024 + d] = a1 + sb[d];
  }
}

// -------- logits: z = LN(Y[:,St-1]) + style, one wave per vocab row --------
__global__ __launch_bounds__(256) void logits_kernel(
    const float* __restrict__ Y, const float* __restrict__ ystats,
    const float* __restrict__ lnw, const float* __restrict__ lnb, int St,
    const float* __restrict__ stylev, const float* __restrict__ Wo,
    const float* __restrict__ bo, const float* __restrict__ tempv,
    float* __restrict__ outl, int t) {
  int wid = threadIdx.x >> 6, lane = threadIdx.x & 63;
  int n = blockIdx.x * 4 + wid;
  const float* wr = Wo + (long long)n * 1024;
  int m0 = St - 1, m1 = St + St - 1;
  const float* y0 = Y + (long long)(St - 1) * 1024;
  const float* y1 = Y + 73728 + (long long)(St - 1) * 1024;
  float mean0 = ystats[2 * m0], rstd0 = ystats[2 * m0 + 1];
  float mean1 = ystats[2 * m1], rstd1 = ystats[2 * m1 + 1];
  float a0 = 0.f, a1 = 0.f;
#pragma unroll
  for (int it = 0; it < 4; ++it) {
    int off = it * 256 + lane * 4;
    float4 wv = *(const float4*)(wr + off);
    float4 lw = *(const float4*)(lnw + off);
    float4 lb = *(const float4*)(lnb + off);
    float4 s0 = *(const float4*)(stylev + off);
    float4 s1 = *(const float4*)(stylev + 1024 + off);
    float4 x0 = *(const float4*)(y0 + off);
    float4 x1 = *(const float4*)(y1 + off);
    float z0x = (x0.x - mean0) * rstd0 * lw.x + lb.x + s0.x;
    float z0y = (x0.y - mean0) * rstd0 * lw.y + lb.y + s0.y;
    float z0z = (x0.z - mean0) * rstd0 * lw.z + lb.z + s0.z;
    float z0w = (x0.w - mean0) * rstd0 * lw.w + lb.w + s0.w;
    float z1x = (x1.x - mean1) * rstd1 * lw.x + lb.x + s1.x;
    float z1y = (x1.y - mean1) * rstd1 * lw.y + lb.y + s1.y;
    float z1z = (x1.z - mean1) * rstd1 * lw.z + lb.z + s1.z;
    float z1w = (x1.w - mean1) * rstd1 * lw.w + lb.w + s1.w;
    a0 += wv.x * z0x + wv.y * z0y + wv.z * z0z + wv.w * z0w;
    a1 += wv.x * z1x + wv.y * z1y + wv.z * z1z + wv.w * z1w;
  }
  a0 = wave_sum(a0);
  a1 = wave_sum(a1);
  if (lane == 0) {
    float bb = bo[n];
    outl[(long long)(0 * 8 + t) * 32000 + n] = (a0 + bb) / tempv[0];
    outl[(long long)(1 * 8 + t) * 32000 + n] = (a1 + bb) / tempv[1];
  }
}

// -------- Gumbel argmax sampling (exact partitionable threefry) + append ----
__global__ __launch_bounds__(1024) void sample_kernel(
    const float* __restrict__ logits, const float* __restrict__ Wo,
    float* __restrict__ tok_f, float* __restrict__ cur, int St,
    uint32_t fk0, uint32_t fk1, int t) {
  int b = blockIdx.x;
  const float* lg = logits + (long long)(b * 8 + t) * 32000;
  float best = -3.4e38f;
  int bi = 0x7fffffff;
  for (int n = threadIdx.x; n < 32000; n += 1024) {
    uint32_t r0, r1;
    threefry2x32(fk0, fk1, 0u, (uint32_t)(b * 32000 + n), &r0, &r1);
    uint32_t bits = (r0 ^ r1) >> 9;
    float u = __uint_as_float(0x3f800000u | bits) - 1.0f;
    if (u < 1.1754944e-38f) u = 1.1754944e-38f;
    float g = -logf(-logf(u));
    float val = lg[n] + g;
    if (val > best) { best = val; bi = n; }
  }
  __shared__ float bv[1024];
  __shared__ int bix[1024];
  bv[threadIdx.x] = best;
  bix[threadIdx.x] = bi;
  __syncthreads();
  for (int s = 512; s > 0; s >>= 1) {
    if (threadIdx.x < s) {
      float ov = bv[threadIdx.x + s];
      int oi = bix[threadIdx.x + s];
      if (ov > bv[threadIdx.x] ||
          (ov == bv[threadIdx.x] && oi < bix[threadIdx.x])) {
        bv[threadIdx.x] = ov;
        bix[threadIdx.x] = oi;
      }
    }
    __syncthreads();
  }
  int tok = bix[0];
  if (threadIdx.x == 0) tok_f[b * 8 + t] = (float)tok;
  cur[(long long)b * 73728 + (long long)St * 1024 + threadIdx.x] =
      Wo[(long long)tok * 1024 + threadIdx.x];
}

// ============================================================================
extern "C" void kernel_launch(void* const* d_in, const int* in_sizes, int n_in,
                              void* d_out, int out_size, void* d_ws,
                              size_t ws_size, hipStream_t stream) {
  const float* emb = (const float*)d_in[0];
  const float* sa_in_w = (const float*)d_in[1];
  const float* sa_in_b = (const float*)d_in[2];
  const float* sa_out_w = (const float*)d_in[3];
  const float* sa_out_b = (const float*)d_in[4];
  const float* ca_in_w = (const float*)d_in[5];
  const float* ca_in_b = (const float*)d_in[6];
  const float* ca_out_w = (const float*)d_in[7];
  const float* ca_out_b = (const float*)d_in[8];
  const float* ff1_w = (const float*)d_in[9];
  const float* ff1_b = (const float*)d_in[10];
  const float* ff2_w = (const float*)d_in[11];
  const float* ff2_b = (const float*)d_in[12];
  const float* ln_w = (const float*)d_in[13];
  const float* ln_b = (const float*)d_in[14];
  const float* out_w = (const float*)d_in[15];
  const float* out_b = (const float*)d_in[16];
  const float* temp_w = (const float*)d_in[17];
  const float* temp_b = (const float*)d_in[18];
  const float* style_w = (const float*)d_in[21];
  const float* style_b = (const float*)d_in[22];

  float* ws = (float*)d_ws;
  float* cur = ws;                          // [2][72][1024]
  float* Qb = cur + 147456;                 // [2][72][3072]
  float* Tb = Qb + 442368;                  // [2][72][1024]
  float* T2 = Tb + 147456;                  // [2][72][1024]
  float* Fb = T2 + 147456;                  // [2][72][4096]
  float* Yb = Fb + 589824;                  // 6 x [2][72][1024]
  float* cakv = Yb + 884736;                // [2][2][64][2048]
  float* Pp = cakv + 524288;                // split-K partials (2.4M floats)
  float* xmean = Pp + 2400000;              // 2048
  float* stylev = xmean + 2048;             // 2048
  float* tempv = stylev + 2048;             // 16
  float* statsb = tempv + 16;               // 6 x 288
  unsigned long long* Srow =
      (unsigned long long*)(statsb + 1728);  // 16 x 144 packed (sum,sumsq)
  int* cntpool = (int*)(Srow + 2304);        // 100 x 256 ints

  float* toks_out = (float*)d_out;
  float* logits_out = toks_out + 16;

  auto Y = [&](int l, int j) { return Yb + (size_t)(l * 3 + j) * 147456; };
  auto SS = [&](int l, int j) { return statsb + (size_t)(l * 3 + j) * 288; };

  // zero the atomic-counter pool (graph node, runs each replay)
  hipMemsetAsync(cntpool, 0, 100 * 256 * sizeof(int), stream);

  int inst = 0;
  auto g3 = [&](const float* X, long long xbs, int ldx, const float* xst,
                const float* xlw, const float* xlb, const float* W, int ldw,
                const float* bias, const float* resY, long long rbs, int ldr,
                const float* rst, const float* rlw, const float* rlb,
                float* out, long long obs, int ldo, float* ost, int St, int M,
                int N, int K, int splits, int relu) {
    dim3 grid((unsigned)((M + 63) / 64), (unsigned)(N / 64),
              (unsigned)splits);
    int* tc = cntpool + inst * 256;
    ++inst;
    gemm3_kernel<<<grid, 256, 0, stream>>>(
        X, xbs, ldx, xst, xlw, xlb, W, ldw, bias, resY, rbs, ldr, rst, rlw,
        rlb, Pp, Srow, out, obs, ldo, ost, St, M, N, K / (32 * splits), relu,
        tc, tc + 200);
  };

  // ---- precompute ----
  copy_cur_kernel<<<512, 256, 0, stream>>>(emb, cur);
  xmean_kernel<<<8, 256, 0, stream>>>(emb, xmean);
  temp_kernel<<<2, 256, 0, stream>>>(emb, temp_w, temp_b, tempv);
  style_kernel<<<256, 256, 0, stream>>>(xmean, style_w, style_b, stylev);
  for (int l = 0; l < 2; ++l)  // cross-attn K,V from constant memory input
    g3(emb, 64 * 1024, 1024, nullptr, nullptr, nullptr,
       ca_in_w + (size_t)(l * 3072 + 1024) * 1024, 1024,
       ca_in_b + l * 3072 + 1024, nullptr, 0, 0, nullptr, nullptr, nullptr,
       cakv + (size_t)l * 2 * 64 * 2048, 64 * 2048, 2048, nullptr, 64, 128,
       2048, 1024, 4, 0);

  for (int t = 0; t < 8; ++t) {
    const int St = 64 + t;
    const int M = 2 * St;
    const int ablk = (2 * 8 * St + 3) / 4;
    for (int l = 0; l < 2; ++l) {
      const float* X0 = (l == 0) ? cur : Y(0, 2);
      const float* X0st = (l == 0) ? nullptr : SS(0, 2);
      const float* X0lw = (l == 0) ? nullptr : ln_w + (0 * 3 + 2) * 1024;
      const float* X0lb = (l == 0) ? nullptr : ln_b + (0 * 3 + 2) * 1024;

      // 1) self-attn QKV (fused bias) -> Qb
      g3(X0, 72 * 1024, 1024, X0st, X0lw, X0lb,
         sa_in_w + (size_t)l * 3072 * 1024, 1024, sa_in_b + l * 3072, nullptr,
         0, 0, nullptr, nullptr, nullptr, Qb, 72 * 3072, 3072, nullptr, St, M,
         3072, 1024, 4, 0);
      // 2) self-attention
      attn_kernel<<<ablk, 256, 0, stream>>>(
          Qb, 3072, 72 * 3072, Qb + 1024, 3072, 72 * 3072, Qb + 2048, 3072,
          72 * 3072, Tb, 1024, 72 * 1024, St, St);
      // 3) out-proj + bias + residual(X0,LN) -> Y0 raw, stats0
      g3(Tb, 72 * 1024, 1024, nullptr, nullptr, nullptr,
         sa_out_w + (size_t)l * 1024 * 1024, 1024, sa_out_b + l * 1024, X0,
         72 * 1024, 1024, X0st, X0lw, X0lb, Y(l, 0), 72 * 1024, 1024,
         SS(l, 0), St, M, 1024, 1024, 8, 0);
      // 4) cross-attn Q = LN(Y0) @ Wq + bq -> T2
      g3(Y(l, 0), 72 * 1024, 1024, SS(l, 0), ln_w + (l * 3 + 0) * 1024,
         ln_b + (l * 3 + 0) * 1024, ca_in_w + (size_t)l * 3072 * 1024, 1024,
         ca_in_b + l * 3072, nullptr, 0, 0, nullptr, nullptr, nullptr, T2,
         72 * 1024, 1024, nullptr, St, M, 1024, 1024, 8, 0);
      // 5) cross-attention
      attn_kernel<<<ablk, 256, 0, stream>>>(
          T2, 1024, 72 * 1024, cakv + (size_t)l * 2 * 64 * 2048, 2048,
          64 * 2048, cakv + (size_t)l * 2 * 64 * 2048 + 1024, 2048, 64 * 2048,
          Tb, 1024, 72 * 1024, St, 64);
      // 6) ca out-proj + bias + residual(LN(Y0)) -> Y1 raw, stats1
      g3(Tb, 72 * 1024, 1024, nullptr, nullptr, nullptr,
         ca_out_w + (size_t)l * 1024 * 1024, 1024, ca_out_b + l * 1024,
         Y(l, 0), 72 * 1024, 1024, SS(l, 0), ln_w + (l * 3 + 0) * 1024,
         ln_b + (l * 3 + 0) * 1024, Y(l, 1), 72 * 1024, 1024, SS(l, 1), St, M,
         1024, 1024, 8, 0);
      // 7) FFN1: relu(LN(Y1) @ W1 + b1) -> Fb
      g3(Y(l, 1), 72 * 1024, 1024, SS(l, 1), ln_w + (l * 3 + 1) * 1024,
         ln_b + (l * 3 + 1) * 1024, ff1_w + (size_t)l * 4096 * 1024, 1024,
         ff1_b + l * 4096, nullptr, 0, 0, nullptr, nullptr, nullptr, Fb,
         72 * 4096, 4096, nullptr, St, M, 4096, 1024, 2, 1);
      // 8) FFN2: Fb @ W2 + b2 + residual(LN(Y1)) -> Y2 raw, stats2
      g3(Fb, 72 * 4096, 4096, nullptr, nullptr, nullptr,
         ff2_w + (size_t)l * 1024 * 4096, 4096, ff2_b + l * 1024, Y(l, 1),
         72 * 1024, 1024, SS(l, 1), ln_w + (l * 3 + 1) * 1024,
         ln_b + (l * 3 + 1) * 1024, Y(l, 2), 72 * 1024, 1024, SS(l, 2), St, M,
         1024, 4096, 8, 0);
    }
    // logits from LN(Y2 of layer 1) + style
    logits_kernel<<<8000, 256, 0, stream>>>(
        Y(1, 2), SS(1, 2), ln_w + (1 * 3 + 2) * 1024,
        ln_b + (1 * 3 + 2) * 1024, St, stylev, out_w, out_b, tempv,
        logits_out, t);
    uint32_t fk0, fk1;
    threefry2x32(0u, 42u, 0u, (uint32_t)t, &fk0, &fk1);
    sample_kernel<<<2, 1024, 0, stream>>>(logits_out, out_w, toks_out, cur,
                                          St, fk0, fk1, t);
  }
}